// Round 6
// baseline (15408.823 us; speedup 1.0000x reference)
//
#include <hip/hip_runtime.h>
#include <stdint.h>

#define T_SEQ 1024
#define BATCH 32
#define HID   512
#define RING  32     // inter-stage ring depth (power of 2)

typedef unsigned short u16;
typedef unsigned long long u64;
typedef short bf16x8 __attribute__((ext_vector_type(8)));
typedef float f32x4  __attribute__((ext_vector_type(4)));

__device__ __forceinline__ float bf2f(u16 u) {
  union { unsigned u; float f; } v; v.u = ((unsigned)u) << 16; return v.f;
}
__device__ __forceinline__ u16 f2bf(float f) {
  union { float f; unsigned u; } v; v.f = f;
  unsigned r = v.u + 0x7fffu + ((v.u >> 16) & 1u);   // RNE
  return (u16)(r >> 16);
}
__device__ __forceinline__ float sigf(float x) { return 1.0f / (1.0f + __expf(-x)); }
__device__ __forceinline__ float tanh_fast(float x) { return 2.0f * sigf(2.0f * x) - 1.0f; }

// Device-scope coherent 8B load/store: bypass stale per-XCD L2, no wbl2/inv.
__device__ __forceinline__ u64 ld_dev(const u64* p) {
  return __hip_atomic_load(p, __ATOMIC_RELAXED, __HIP_MEMORY_SCOPE_AGENT);
}
__device__ __forceinline__ void st_dev(u64* p, u64 v) {
  __hip_atomic_store(p, v, __ATOMIC_RELAXED, __HIP_MEMORY_SCOPE_AGENT);
}
__device__ __forceinline__ int ld_flag(const int* p) {
  return __hip_atomic_load(p, __ATOMIC_RELAXED, __HIP_MEMORY_SCOPE_AGENT);
}

// ---------------- cast fp32 -> bf16 ----------------
__global__ __launch_bounds__(256) void cast_f32_bf16(const float* __restrict__ in,
                                                     u16* __restrict__ out, int n) {
  int i = (blockIdx.x * 256 + threadIdx.x) * 8;
  if (i + 7 < n) {
    float4 v0 = *reinterpret_cast<const float4*>(in + i);
    float4 v1 = *reinterpret_cast<const float4*>(in + i + 4);
    uint4 o;
    o.x = (unsigned)f2bf(v0.x) | ((unsigned)f2bf(v0.y) << 16);
    o.y = (unsigned)f2bf(v0.z) | ((unsigned)f2bf(v0.w) << 16);
    o.z = (unsigned)f2bf(v1.x) | ((unsigned)f2bf(v1.y) << 16);
    o.w = (unsigned)f2bf(v1.z) | ((unsigned)f2bf(v1.w) << 16);
    *reinterpret_cast<uint4*>(out + i) = o;
  } else {
    for (; i < n; ++i) out[i] = f2bf(in[i]);
  }
}

// ---------------- prep: W' = bf16(W ∘ g), Gn = Σ g*W, Bn = Σ b*W ----------------
__global__ __launch_bounds__(256) void prep_wih(
    const float* __restrict__ w, const float* __restrict__ g, const float* __restrict__ b,
    u16* __restrict__ wout, float* __restrict__ Gn, float* __restrict__ Bn, int N)
{
  int row  = blockIdx.x * 4 + (threadIdx.x >> 6);
  int lane = threadIdx.x & 63;
  if (row >= N) return;
  const float* wr = w + (long)row * 512 + lane * 8;
  float sg = 0.f, sb = 0.f;
  u16 o[8];
#pragma unroll
  for (int i = 0; i < 8; ++i) {
    float wv = wr[i];
    float gv = g[lane * 8 + i];
    float bv = b[lane * 8 + i];
    o[i] = f2bf(wv * gv);
    sg += wv * gv;
    sb += wv * bv;
  }
  *reinterpret_cast<uint4*>(wout + (long)row * 512 + lane * 8) = *reinterpret_cast<uint4*>(o);
#pragma unroll
  for (int off = 1; off < 64; off <<= 1) { sg += __shfl_xor(sg, off); sb += __shfl_xor(sb, off); }
  if (lane == 0) { Gn[row] = sg; Bn[row] = sb; }
}

// ---------------- LSTM input GEMM: out[t][b][k][g] = x @ w_ih^T + b_ih + b_hh ----------------
__global__ __launch_bounds__(256) void gemm_xg(
    const u16* __restrict__ A, const u16* __restrict__ W,
    const float* __restrict__ bias1, const float* __restrict__ bias2,
    u16* __restrict__ out, int N, int K, int strideB, int strideT)
{
  __shared__ u16 As[64][72];
  __shared__ u16 Bs[64][72];
  int tid  = threadIdx.x;
  int lane = tid & 63;
  int wave = tid >> 6;
  int m0 = blockIdx.x * 64;
  int n0 = blockIdx.y * 64;

  f32x4 zero = {0.f, 0.f, 0.f, 0.f};
  f32x4 acc[4] = {zero, zero, zero, zero};

  int srow = tid >> 2;
  int scol = (tid & 3) * 16;

  int m_s = m0 + srow;
  long arow = (long)(m_s & (BATCH - 1)) * strideB + (long)(m_s >> 5) * strideT;
  const u16* aptr = A + arow * K + scol;
  const u16* wptr = W + (long)(n0 + srow) * K + scol;

  for (int kk = 0; kk < K; kk += 64) {
    __syncthreads();
    uint4 a0 = *reinterpret_cast<const uint4*>(aptr + kk);
    uint4 a1 = *reinterpret_cast<const uint4*>(aptr + kk + 8);
    uint4 b0 = *reinterpret_cast<const uint4*>(wptr + kk);
    uint4 b1 = *reinterpret_cast<const uint4*>(wptr + kk + 8);
    *reinterpret_cast<uint4*>(&As[srow][scol])     = a0;
    *reinterpret_cast<uint4*>(&As[srow][scol + 8]) = a1;
    *reinterpret_cast<uint4*>(&Bs[srow][scol])     = b0;
    *reinterpret_cast<uint4*>(&Bs[srow][scol + 8]) = b1;
    __syncthreads();
    int am = wave * 16 + (lane & 15);
    int kq = (lane >> 4) * 8;
#pragma unroll
    for (int ks = 0; ks < 2; ++ks) {
      bf16x8 af = *reinterpret_cast<const bf16x8*>(&As[am][kq + ks * 32]);
#pragma unroll
      for (int nb = 0; nb < 4; ++nb) {
        bf16x8 bf = *reinterpret_cast<const bf16x8*>(&Bs[nb * 16 + (lane & 15)][kq + ks * 32]);
        acc[nb] = __builtin_amdgcn_mfma_f32_16x16x32_bf16(af, bf, acc[nb], 0, 0, 0);
      }
    }
  }
  int quad = lane >> 4;
#pragma unroll
  for (int nb = 0; nb < 4; ++nb) {
    int n = n0 + nb * 16 + (lane & 15);
    float bv = bias1[n] + (bias2 ? bias2[n] : 0.0f);
    int g = n >> 9, k = n & 511;
#pragma unroll
    for (int r = 0; r < 4; ++r) {
      int m = m0 + wave * 16 + quad * 4 + r;
      int t = m >> 5, b = m & (BATCH - 1);
      out[(((long)t * BATCH + b) * HID + k) * 4 + g] = f2bf(acc[nb][r] + bv);
    }
  }
}

// 16x16x32 K=512 fragment GEMM, both operands from LDS.
__device__ __forceinline__ f32x4 frag_lds(const u16 (*a)[520], int arow, int kq,
                                          const u16 (*w)[520], int wrow) {
  f32x4 a0 = {0.f,0.f,0.f,0.f}, a1 = {0.f,0.f,0.f,0.f};
#pragma unroll
  for (int ks = 0; ks < 16; ++ks) {
    bf16x8 av = *reinterpret_cast<const bf16x8*>(&a[arow][kq + ks * 32]);
    bf16x8 bv = *reinterpret_cast<const bf16x8*>(&w[wrow][kq + ks * 32]);
    if (ks & 1) a1 = __builtin_amdgcn_mfma_f32_16x16x32_bf16(av, bv, a1, 0, 0, 0);
    else        a0 = __builtin_amdgcn_mfma_f32_16x16x32_bf16(av, bv, a0, 0, 0, 0);
  }
  return a0 + a1;
}

// ---------------- persistent recurrent role (ROLE: 0=LSTM 1=GRU 2=RNN) ----------------
// h exchanged via device-scope atomics; each step the WG cooperatively stages
// the needed h rows (own and upstream) into LDS, then MFMA reads fragments
// from LDS. LayerNorm is algebraically folded into the GRU/RNN input GEMM.
template <int ROLE>
__device__ void recur_role(
    int wg, const u16* __restrict__ xg, const u16* __restrict__ up,
    const u16* __restrict__ wih, const u16* __restrict__ whh,
    const float* __restrict__ bih, const float* __restrict__ bhh,
    const float* __restrict__ Gn, const float* __restrict__ Bn,
    u16* __restrict__ hist, const int* fl_up, int* fl_own, const int* cons,
    u16 (*w_lds)[520], u16 (*st_up)[520], u16 (*st_own)[520],
    float (*gx)[33], float (*gh)[33], float* stats, u16 (*hs)[8])
{
  constexpr int NG = (ROLE == 0) ? 4 : (ROLE == 1) ? 3 : 1;
  constexpr int NPAD = (ROLE == 2) ? 16 : 32;
  constexpr int XROWS = (ROLE > 0) ? NG * 8 : 0;   // x-weight rows staged
  constexpr int TOT = XROWS + NG * 8;
  constexpr int RH = (ROLE == 2) ? 2 : RING;
  int tid = threadIdx.x, lane = tid & 63, wave = tid >> 6;
  int hbase = wg * 8;

  // stage weights: rows [0,XROWS) = g∘W_ih slice, [XROWS,TOT) = W_hh slice
  for (int idx = tid; idx < TOT * 64; idx += 256) {
    int row = idx >> 6, chunk = idx & 63;
    int n = (row < XROWS) ? row : (row - XROWS);
    const u16* src = (row < XROWS) ? wih : whh;
    int g = n >> 3, dd = n & 7;
    uint4 v = *reinterpret_cast<const uint4*>(src + ((long)(g * 512 + hbase + dd)) * 512 + chunk * 8);
    *reinterpret_cast<uint4*>(&w_lds[row][chunk * 8]) = v;
  }
  __syncthreads();

  int mt = wave & 1, nt = wave >> 1;
  bool mact = (nt * 16) < NPAD;
  int colw = nt * 16 + (lane & 15);
  int wr = (colw < NG * 8) ? colw : (NG * 8 - 1);   // clamped B row (cols>=NG*8 unused)
  int arow = mt * 16 + (lane & 15);
  int kq = (lane >> 4) * 8;
  int quad = lane >> 4;
  float Gw = 0.f, bxc = 0.f, bhw = 0.f;
  if (mact && colw < NG * 8) {
    int g = colw >> 3, dd = colw & 7;
    int n = g * 512 + hbase + dd;
    if constexpr (ROLE == 1) { Gw = Gn[n]; bxc = Bn[n] + bih[n]; bhw = bhh[n]; }
    if constexpr (ROLE == 2) { Gw = Gn[n]; bxc = Bn[n] + bih[n] + bhh[n]; }
    (void)g;
  }
  int b_c = tid >> 3, d_c = tid & 7;   // cell thread owns h[b_c][hbase+d_c]
  int srow = tid >> 3;                 // staging: 32 rows x 8 threads
  int scol = (tid & 7) * 64;           // 64 bf16 (128B) per thread
  float c_st = 0.f, h_st = 0.f;

  for (int t = 0; t < T_SEQ; ++t) {
    u64 xq = 0;
    if constexpr (ROLE == 0)
      xq = *reinterpret_cast<const u64*>(xg + (((long)t * BATCH + b_c) * HID + hbase + d_c) * 4);

    // ---- stage own h_{t-1}: poll (all waves), issue loads into registers ----
    u64 qo[16];
    if (t > 0) {
      while (true) {
        int f = ld_flag(&fl_own[lane]);
        if (__all(f >= t)) break;
        __builtin_amdgcn_s_sleep(1);
      }
      __asm__ volatile("" ::: "memory");
      const u64* p = reinterpret_cast<const u64*>(
          hist + ((long)((t - 1) & (RH - 1)) * BATCH + srow) * HID + scol);
#pragma unroll
      for (int i = 0; i < 16; ++i) qo[i] = ld_dev(p + i);
    }
    // ---- stage upstream h (own loads still in flight during this poll) ----
    if constexpr (ROLE > 0) {
      while (true) {
        int f = ld_flag(&fl_up[lane]);
        if (__all(f >= t + 1)) break;
        __builtin_amdgcn_s_sleep(1);
      }
      __asm__ volatile("" ::: "memory");
      const u64* p = reinterpret_cast<const u64*>(
          up + ((long)(t & (RING - 1)) * BATCH + srow) * HID + scol);
      u64 qu[16];
#pragma unroll
      for (int i = 0; i < 16; ++i) qu[i] = ld_dev(p + i);
      // row stats for fused LN (on raw upstream h)
      float s = 0.f, s2 = 0.f;
#pragma unroll
      for (int i = 0; i < 16; ++i) {
        unsigned d0 = (unsigned)qu[i], d1 = (unsigned)(qu[i] >> 32);
        union { unsigned u; float f; } a, b, c, d;
        a.u = d0 << 16; b.u = d0 & 0xffff0000u;
        c.u = d1 << 16; d.u = d1 & 0xffff0000u;
        s  += (a.f + b.f) + (c.f + d.f);
        s2 += (a.f * a.f + b.f * b.f) + (c.f * c.f + d.f * d.f);
      }
      s  += __shfl_xor(s, 1);  s  += __shfl_xor(s, 2);  s  += __shfl_xor(s, 4);
      s2 += __shfl_xor(s2, 1); s2 += __shfl_xor(s2, 2); s2 += __shfl_xor(s2, 4);
      if ((tid & 7) == 0) { stats[srow * 2] = s; stats[srow * 2 + 1] = s2; }
#pragma unroll
      for (int i = 0; i < 8; ++i) {
        uint4 v;
        v.x = (unsigned)qu[2 * i];     v.y = (unsigned)(qu[2 * i] >> 32);
        v.z = (unsigned)qu[2 * i + 1]; v.w = (unsigned)(qu[2 * i + 1] >> 32);
        *reinterpret_cast<uint4*>(&st_up[srow][scol + i * 8]) = v;
      }
    }
    if (t > 0) {
#pragma unroll
      for (int i = 0; i < 8; ++i) {
        uint4 v;
        v.x = (unsigned)qo[2 * i];     v.y = (unsigned)(qo[2 * i] >> 32);
        v.z = (unsigned)qo[2 * i + 1]; v.w = (unsigned)(qo[2 * i + 1] >> 32);
        *reinterpret_cast<uint4*>(&st_own[srow][scol + i * 8]) = v;
      }
    }
    __syncthreads();

    // ---- MFMA from LDS ----
    if (mact) {
      f32x4 aX = {0.f,0.f,0.f,0.f}, aH = {0.f,0.f,0.f,0.f};
      if constexpr (ROLE > 0)
        aX = frag_lds(st_up, arow, kq, w_lds, wr);
      if (t > 0)
        aH = frag_lds(st_own, arow, kq, w_lds + XROWS, wr);
      if constexpr (ROLE > 0) {
#pragma unroll
        for (int r = 0; r < 4; ++r) {
          int row = mt * 16 + quad * 4 + r;
          float s = stats[row * 2], s2 = stats[row * 2 + 1];
          float mu = s * (1.f / 512.f);
          float var = s2 * (1.f / 512.f) - mu * mu;
          float rs = rsqrtf(var + 1e-5f);
          gx[row][colw] = rs * aX[r] - rs * mu * Gw + bxc;
          gh[row][colw] = aH[r] + bhw;
        }
      } else {
#pragma unroll
        for (int r = 0; r < 4; ++r) {
          int row = mt * 16 + quad * 4 + r;
          gh[row][colw] = aH[r];
        }
      }
    }
    __syncthreads();

    // ---- cell ----
    float hnew;
    if constexpr (ROLE == 0) {
      float xv0 = bf2f((u16)(xq));
      float xv1 = bf2f((u16)(xq >> 16));
      float xv2 = bf2f((u16)(xq >> 32));
      float xv3 = bf2f((u16)(xq >> 48));
      float h0 = gh[b_c][0 * 8 + d_c];
      float h1 = gh[b_c][1 * 8 + d_c];
      float h2 = gh[b_c][2 * 8 + d_c];
      float h3 = gh[b_c][3 * 8 + d_c];
      float ig = sigf(xv0 + h0), fg = sigf(xv1 + h1);
      float gg = tanh_fast(xv2 + h2), og = sigf(xv3 + h3);
      c_st = fg * c_st + ig * gg;
      hnew = og * tanh_fast(c_st);
    } else if constexpr (ROLE == 1) {
      float xr_ = gx[b_c][0 * 8 + d_c], xz = gx[b_c][1 * 8 + d_c], xn = gx[b_c][2 * 8 + d_c];
      float hr  = gh[b_c][0 * 8 + d_c], hz = gh[b_c][1 * 8 + d_c], hn = gh[b_c][2 * 8 + d_c];
      float r = sigf(xr_ + hr), z = sigf(xz + hz);
      float n = tanh_fast(xn + r * hn);
      hnew = (1.f - z) * n + z * h_st;
      h_st = hnew;
    } else {
      hnew = tanh_fast(gx[b_c][d_c] + gh[b_c][d_c]);
    }
    hs[b_c][d_c] = f2bf(hnew);
    __syncthreads();

    // ---- publish (wave0) ----
    if (wave == 0) {
      if (cons != nullptr && t >= RH) {   // ring back-pressure (rarely binds)
        int tgt = t - RH + 1;
        while (true) {
          int f = ld_flag(&cons[lane]);
          if (__all(f >= tgt)) break;
          __builtin_amdgcn_s_sleep(1);
        }
      }
      int pb = lane >> 1, half = lane & 1;
      u64 val = *reinterpret_cast<const u64*>(&hs[pb][half * 4]);
      st_dev(reinterpret_cast<u64*>(hist + ((long)(t & (RH - 1)) * BATCH + pb) * HID + hbase + half * 4), val);
      __asm__ volatile("s_waitcnt vmcnt(0)" ::: "memory");
      if (tid == 0)
        __hip_atomic_store(&fl_own[wg], t + 1, __ATOMIC_RELAXED, __HIP_MEMORY_SCOPE_AGENT);
    }
  }
}

// LDS carve offsets (bytes)
#define SM_W    0
#define SM_UP   49920
#define SM_OWN  83200
#define SM_GX   116480
#define SM_GH   120704
#define SM_ST   124928
#define SM_HS   125184
#define SM_TOT  125696

// ---------------- fused pipeline kernel: 192 WGs ----------------
// flags: [0..63] lstm, [64..127] gru, [128..191] rnn
__global__ __launch_bounds__(256) void fused_kernel(
    const u16* __restrict__ xg, const u16* __restrict__ lstm_whh,
    const u16* __restrict__ gru_wih, const u16* __restrict__ gru_whh,
    const float* __restrict__ gru_bih, const float* __restrict__ gru_bhh,
    const float* __restrict__ G1, const float* __restrict__ B1,
    const u16* __restrict__ rnn_wih, const u16* __restrict__ rnn_whh,
    const float* __restrict__ rnn_bih, const float* __restrict__ rnn_bhh,
    const float* __restrict__ G2, const float* __restrict__ B2,
    u16* h1, u16* h2, u16* h3, int* fl)
{
  extern __shared__ char smem[];
  u16 (*w_lds)[520]  = reinterpret_cast<u16(*)[520]>(smem + SM_W);
  u16 (*st_up)[520]  = reinterpret_cast<u16(*)[520]>(smem + SM_UP);
  u16 (*st_own)[520] = reinterpret_cast<u16(*)[520]>(smem + SM_OWN);
  float (*gx)[33]    = reinterpret_cast<float(*)[33]>(smem + SM_GX);
  float (*gh)[33]    = reinterpret_cast<float(*)[33]>(smem + SM_GH);
  float* stats       = reinterpret_cast<float*>(smem + SM_ST);
  u16 (*hs)[8]       = reinterpret_cast<u16(*)[8]>(smem + SM_HS);
  int bid = blockIdx.x;
  if (bid < 64)
    recur_role<0>(bid, xg, nullptr, nullptr, lstm_whh, nullptr, nullptr, nullptr, nullptr,
                  h1, nullptr, fl + 0, fl + 64, w_lds, st_up, st_own, gx, gh, stats, hs);
  else if (bid < 128)
    recur_role<1>(bid - 64, nullptr, h1, gru_wih, gru_whh, gru_bih, gru_bhh, G1, B1,
                  h2, fl + 0, fl + 64, fl + 128, w_lds, st_up, st_own, gx, gh, stats, hs);
  else
    recur_role<2>(bid - 128, nullptr, h2, rnn_wih, rnn_whh, rnn_bih, rnn_bhh, G2, B2,
                  h3, fl + 64, fl + 128, nullptr, w_lds, st_up, st_own, gx, gh, stats, hs);
}

// ---------------- final FC ----------------
__global__ __launch_bounds__(256) void fc_kernel(
    const u16* __restrict__ hlast, const u16* __restrict__ w,
    const float* __restrict__ bias, float* __restrict__ out)
{
  int tg = blockIdx.x * 256 + threadIdx.x;
  if (tg >= BATCH * 1000) return;
  int b = tg / 1000, o = tg % 1000;
  const u16* hp = hlast + (long)b * HID;
  const u16* wp = w + (long)o * HID;
  float acc = 0.f;
  for (int k = 0; k < HID; k += 8) {
    uint4 hu = *reinterpret_cast<const uint4*>(hp + k);
    uint4 wu = *reinterpret_cast<const uint4*>(wp + k);
    u16* hsv = reinterpret_cast<u16*>(&hu);
    u16* wsv = reinterpret_cast<u16*>(&wu);
#pragma unroll
    for (int i = 0; i < 8; ++i) acc += bf2f(hsv[i]) * bf2f(wsv[i]);
  }
  out[tg] = acc + bias[o];
}

__global__ void sentinel_kernel(float* out) { out[0] = 12345.0f; }

// ---------------- launch ----------------
extern "C" void kernel_launch(void* const* d_in, const int* in_sizes, int n_in,
                              void* d_out, int out_size, void* d_ws, size_t ws_size,
                              hipStream_t stream)
{
  (void)in_sizes; (void)n_in; (void)out_size;
  const float* x        = (const float*)d_in[0];
  const float* lstm_wih = (const float*)d_in[1];
  const float* lstm_whh = (const float*)d_in[2];
  const float* lstm_bih = (const float*)d_in[3];
  const float* lstm_bhh = (const float*)d_in[4];
  const float* ln1_g    = (const float*)d_in[5];
  const float* ln1_b    = (const float*)d_in[6];
  const float* gru_wih  = (const float*)d_in[7];
  const float* gru_whh  = (const float*)d_in[8];
  const float* gru_bih  = (const float*)d_in[9];
  const float* gru_bhh  = (const float*)d_in[10];
  const float* ln2_g    = (const float*)d_in[11];
  const float* ln2_b    = (const float*)d_in[12];
  const float* rnn_wih  = (const float*)d_in[13];
  const float* rnn_whh  = (const float*)d_in[14];
  const float* rnn_bih  = (const float*)d_in[15];
  const float* rnn_bhh  = (const float*)d_in[16];
  const float* fc_w     = (const float*)d_in[17];
  const float* fc_b     = (const float*)d_in[18];
  float* out = (float*)d_out;

  char* ws = (char*)d_ws;
  size_t off = 0;
  auto alloc = [&](size_t bytes) -> void* {
    void* p = ws + off; off += (bytes + 255) & ~(size_t)255; return p;
  };
  int* flags     = (int*)alloc(192 * sizeof(int));
  u16* xbf       = (u16*)alloc((size_t)BATCH * T_SEQ * 256 * 2);
  u16* lstm_wih_b= (u16*)alloc((size_t)2048 * 256 * 2);
  u16* lstm_whh_b= (u16*)alloc((size_t)2048 * 512 * 2);
  u16* gru_wih_b = (u16*)alloc((size_t)1536 * 512 * 2);
  u16* gru_whh_b = (u16*)alloc((size_t)1536 * 512 * 2);
  u16* rnn_wih_b = (u16*)alloc((size_t)512 * 512 * 2);
  u16* rnn_whh_b = (u16*)alloc((size_t)512 * 512 * 2);
  u16* fc_w_b    = (u16*)alloc((size_t)1000 * 512 * 2);
  float* G1      = (float*)alloc(1536 * sizeof(float));
  float* B1      = (float*)alloc(1536 * sizeof(float));
  float* G2      = (float*)alloc(512 * sizeof(float));
  float* B2      = (float*)alloc(512 * sizeof(float));
  u16* xg2       = (u16*)alloc((size_t)T_SEQ * BATCH * HID * 4 * 2);  // 128 MB
  u16* h1        = (u16*)alloc((size_t)RING * BATCH * HID * 2);       // 1 MB rings
  u16* h2        = (u16*)alloc((size_t)RING * BATCH * HID * 2);
  u16* h3        = (u16*)alloc((size_t)2 * BATCH * HID * 2);          // ping-pong

  if (off > ws_size) {
    sentinel_kernel<<<1, 1, 0, stream>>>(out);
    return;
  }

  hipMemsetAsync(flags, 0, 192 * sizeof(int), stream);

  auto cast = [&](const float* src, u16* dst, int n) {
    cast_f32_bf16<<<(n + 2047) / 2048, 256, 0, stream>>>(src, dst, n);
  };
  cast(x,        xbf,        BATCH * T_SEQ * 256);
  cast(lstm_wih, lstm_wih_b, 2048 * 256);
  cast(lstm_whh, lstm_whh_b, 2048 * 512);
  cast(gru_whh,  gru_whh_b,  1536 * 512);
  cast(rnn_whh,  rnn_whh_b,  512 * 512);
  cast(fc_w,     fc_w_b,     1000 * 512);

  // LN-folded input weights: W' = bf16(W ∘ g), Gn = Σ g*W, Bn = Σ b*W
  prep_wih<<<1536 / 4, 256, 0, stream>>>(gru_wih, ln1_g, ln1_b, gru_wih_b, G1, B1, 1536);
  prep_wih<<<512 / 4, 256, 0, stream>>>(rnn_wih, ln2_g, ln2_b, rnn_wih_b, G2, B2, 512);

  const int M64 = (BATCH * T_SEQ) / 64;  // 512
  gemm_xg<<<dim3(M64, 2048 / 64), 256, 0, stream>>>(
      xbf, lstm_wih_b, lstm_bih, lstm_bhh, xg2, 2048, 256, 1024, 1);

  // dynamic LDS 125.7 KB -> 1 WG/CU; 192 WGs on 256 CUs (all co-resident)
  static bool attr_set = false;
  if (!attr_set) {
    hipFuncSetAttribute(reinterpret_cast<const void*>(&fused_kernel),
                        hipFuncAttributeMaxDynamicSharedMemorySize, SM_TOT);
    attr_set = true;
  }
  fused_kernel<<<192, 256, SM_TOT, stream>>>(
      xg2, lstm_whh_b,
      gru_wih_b, gru_whh_b, gru_bih, gru_bhh, G1, B1,
      rnn_wih_b, rnn_whh_b, rnn_bih, rnn_bhh, G2, B2,
      h1, h2, h3, flags);

  // h3 last written slot = (T_SEQ-1)&1 = 1
  fc_kernel<<<(BATCH * 1000 + 255) / 256, 256, 0, stream>>>(
      h3 + (size_t)BATCH * HID, fc_w_b, fc_b, out);
}

// Round 7
// 11376.938 us; speedup vs baseline: 1.3544x; 1.3544x over previous
//
#include <hip/hip_runtime.h>
#include <stdint.h>

#define T_SEQ 1024
#define BATCH 32
#define HID   512
#define RING  32     // inter-stage ring depth (power of 2)

typedef unsigned short u16;
typedef unsigned long long u64;
typedef short bf16x8 __attribute__((ext_vector_type(8)));
typedef float f32x4  __attribute__((ext_vector_type(4)));

__device__ __forceinline__ float bf2f(u16 u) {
  union { unsigned u; float f; } v; v.u = ((unsigned)u) << 16; return v.f;
}
__device__ __forceinline__ u16 f2bf(float f) {
  union { float f; unsigned u; } v; v.f = f;
  unsigned r = v.u + 0x7fffu + ((v.u >> 16) & 1u);   // RNE
  return (u16)(r >> 16);
}
__device__ __forceinline__ float sigf(float x) { return 1.0f / (1.0f + __expf(-x)); }
__device__ __forceinline__ float tanh_fast(float x) { return 2.0f * sigf(2.0f * x) - 1.0f; }

// Device-scope coherent 8B load/store: bypass stale per-XCD L2, no wbl2/inv.
__device__ __forceinline__ u64 ld_dev(const u64* p) {
  return __hip_atomic_load(p, __ATOMIC_RELAXED, __HIP_MEMORY_SCOPE_AGENT);
}
__device__ __forceinline__ void st_dev(u64* p, u64 v) {
  __hip_atomic_store(p, v, __ATOMIC_RELAXED, __HIP_MEMORY_SCOPE_AGENT);
}
__device__ __forceinline__ int ld_flag(const int* p) {
  return __hip_atomic_load(p, __ATOMIC_RELAXED, __HIP_MEMORY_SCOPE_AGENT);
}

// ---------------- cast fp32 -> bf16 ----------------
__global__ __launch_bounds__(256) void cast_f32_bf16(const float* __restrict__ in,
                                                     u16* __restrict__ out, int n) {
  int i = (blockIdx.x * 256 + threadIdx.x) * 8;
  if (i + 7 < n) {
    float4 v0 = *reinterpret_cast<const float4*>(in + i);
    float4 v1 = *reinterpret_cast<const float4*>(in + i + 4);
    uint4 o;
    o.x = (unsigned)f2bf(v0.x) | ((unsigned)f2bf(v0.y) << 16);
    o.y = (unsigned)f2bf(v0.z) | ((unsigned)f2bf(v0.w) << 16);
    o.z = (unsigned)f2bf(v1.x) | ((unsigned)f2bf(v1.y) << 16);
    o.w = (unsigned)f2bf(v1.z) | ((unsigned)f2bf(v1.w) << 16);
    *reinterpret_cast<uint4*>(out + i) = o;
  } else {
    for (; i < n; ++i) out[i] = f2bf(in[i]);
  }
}

// ---------------- prep: W' = bf16(W ∘ g), Gn = Σ g*W, Bn = Σ b*W ----------------
__global__ __launch_bounds__(256) void prep_wih(
    const float* __restrict__ w, const float* __restrict__ g, const float* __restrict__ b,
    u16* __restrict__ wout, float* __restrict__ Gn, float* __restrict__ Bn, int N)
{
  int row  = blockIdx.x * 4 + (threadIdx.x >> 6);
  int lane = threadIdx.x & 63;
  if (row >= N) return;
  const float* wr = w + (long)row * 512 + lane * 8;
  float sg = 0.f, sb = 0.f;
  u16 o[8];
#pragma unroll
  for (int i = 0; i < 8; ++i) {
    float wv = wr[i];
    float gv = g[lane * 8 + i];
    float bv = b[lane * 8 + i];
    o[i] = f2bf(wv * gv);
    sg += wv * gv;
    sb += wv * bv;
  }
  *reinterpret_cast<uint4*>(wout + (long)row * 512 + lane * 8) = *reinterpret_cast<uint4*>(o);
#pragma unroll
  for (int off = 1; off < 64; off <<= 1) { sg += __shfl_xor(sg, off); sb += __shfl_xor(sb, off); }
  if (lane == 0) { Gn[row] = sg; Bn[row] = sb; }
}

// ---------------- LSTM input GEMM: out[t][b][k][g] = x @ w_ih^T + b_ih + b_hh ----------------
__global__ __launch_bounds__(256) void gemm_xg(
    const u16* __restrict__ A, const u16* __restrict__ W,
    const float* __restrict__ bias1, const float* __restrict__ bias2,
    u16* __restrict__ out, int N, int K, int strideB, int strideT)
{
  __shared__ u16 As[64][72];
  __shared__ u16 Bs[64][72];
  int tid  = threadIdx.x;
  int lane = tid & 63;
  int wave = tid >> 6;
  int m0 = blockIdx.x * 64;
  int n0 = blockIdx.y * 64;

  f32x4 zero = {0.f, 0.f, 0.f, 0.f};
  f32x4 acc[4] = {zero, zero, zero, zero};

  int srow = tid >> 2;
  int scol = (tid & 3) * 16;

  int m_s = m0 + srow;
  long arow = (long)(m_s & (BATCH - 1)) * strideB + (long)(m_s >> 5) * strideT;
  const u16* aptr = A + arow * K + scol;
  const u16* wptr = W + (long)(n0 + srow) * K + scol;

  for (int kk = 0; kk < K; kk += 64) {
    __syncthreads();
    uint4 a0 = *reinterpret_cast<const uint4*>(aptr + kk);
    uint4 a1 = *reinterpret_cast<const uint4*>(aptr + kk + 8);
    uint4 b0 = *reinterpret_cast<const uint4*>(wptr + kk);
    uint4 b1 = *reinterpret_cast<const uint4*>(wptr + kk + 8);
    *reinterpret_cast<uint4*>(&As[srow][scol])     = a0;
    *reinterpret_cast<uint4*>(&As[srow][scol + 8]) = a1;
    *reinterpret_cast<uint4*>(&Bs[srow][scol])     = b0;
    *reinterpret_cast<uint4*>(&Bs[srow][scol + 8]) = b1;
    __syncthreads();
    int am = wave * 16 + (lane & 15);
    int kq = (lane >> 4) * 8;
#pragma unroll
    for (int ks = 0; ks < 2; ++ks) {
      bf16x8 af = *reinterpret_cast<const bf16x8*>(&As[am][kq + ks * 32]);
#pragma unroll
      for (int nb = 0; nb < 4; ++nb) {
        bf16x8 bf = *reinterpret_cast<const bf16x8*>(&Bs[nb * 16 + (lane & 15)][kq + ks * 32]);
        acc[nb] = __builtin_amdgcn_mfma_f32_16x16x32_bf16(af, bf, acc[nb], 0, 0, 0);
      }
    }
  }
  int quad = lane >> 4;
#pragma unroll
  for (int nb = 0; nb < 4; ++nb) {
    int n = n0 + nb * 16 + (lane & 15);
    float bv = bias1[n] + (bias2 ? bias2[n] : 0.0f);
    int g = n >> 9, k = n & 511;
#pragma unroll
    for (int r = 0; r < 4; ++r) {
      int m = m0 + wave * 16 + quad * 4 + r;
      int t = m >> 5, b = m & (BATCH - 1);
      out[(((long)t * BATCH + b) * HID + k) * 4 + g] = f2bf(acc[nb][r] + bv);
    }
  }
}

// 16x16x32 K=512 fragment GEMM: A rows from coherent global, B from LDS region.
// STATS: also accumulate Σx, Σx² of this lane's 128 A elements (for fused LN).
template <bool STATS>
__device__ __forceinline__ f32x4 frag_gemm(const u16* aptr, int kq,
                                           const u16 (*w)[520], int wrow,
                                           float& s, float& s2) {
  const u64* xp = reinterpret_cast<const u64*>(aptr);
  f32x4 a0 = {0.f,0.f,0.f,0.f}, a1 = {0.f,0.f,0.f,0.f};
#pragma unroll
  for (int ks = 0; ks < 16; ++ks) {
    union { u64 q[2]; unsigned d[4]; bf16x8 v; } c;
    c.q[0] = ld_dev(xp + ks * 8);
    c.q[1] = ld_dev(xp + ks * 8 + 1);
    if (STATS) {
#pragma unroll
      for (int i = 0; i < 4; ++i) {
        union { unsigned u; float f; } lo, hi;
        lo.u = c.d[i] << 16;
        hi.u = c.d[i] & 0xffff0000u;
        s  += lo.f + hi.f;
        s2 += lo.f * lo.f + hi.f * hi.f;
      }
    }
    bf16x8 bfr = *reinterpret_cast<const bf16x8*>(&w[wrow][kq + ks * 32]);
    if (ks & 1) a1 = __builtin_amdgcn_mfma_f32_16x16x32_bf16(c.v, bfr, a1, 0, 0, 0);
    else        a0 = __builtin_amdgcn_mfma_f32_16x16x32_bf16(c.v, bfr, a0, 0, 0, 0);
  }
  return a0 + a1;
}

// ---------------- persistent recurrent role (ROLE: 0=LSTM 1=GRU 2=RNN) ----------------
// R4 poll structure (each mact wave polls independently, loads straight from
// coherent global into MFMA fragments) + LN folded algebraically into the
// GRU/RNN input GEMM (pre-scaled g∘W weights, in-flight row stats, Gn/Bn fixup).
template <int ROLE>
__device__ void recur_role(
    int wg, const u16* __restrict__ xg, const u16* __restrict__ up,
    const u16* __restrict__ wih, const u16* __restrict__ whh,
    const float* __restrict__ bih, const float* __restrict__ bhh,
    const float* __restrict__ Gn, const float* __restrict__ Bn,
    u16* __restrict__ hist, const int* fl_up, int* fl_own, const int* cons,
    u16 (*w_lds)[520], float (*gx)[33], float (*gh)[33], u16 (*hs)[8])
{
  constexpr int NG = (ROLE == 0) ? 4 : (ROLE == 1) ? 3 : 1;
  constexpr int NPAD = (ROLE == 2) ? 16 : 32;
  constexpr int XROWS = (ROLE > 0) ? NG * 8 : 0;   // x-weight rows staged
  constexpr int TOT = XROWS + NG * 8;
  constexpr int RH = (ROLE == 2) ? 2 : RING;
  int tid = threadIdx.x, lane = tid & 63, wave = tid >> 6;
  int hbase = wg * 8;

  // stage weights: rows [0,XROWS) = g∘W_ih slice, [XROWS,TOT) = W_hh slice
  for (int idx = tid; idx < TOT * 64; idx += 256) {
    int row = idx >> 6, chunk = idx & 63;
    int n = (row < XROWS) ? row : (row - XROWS);
    const u16* src = (row < XROWS) ? wih : whh;
    int g = n >> 3, dd = n & 7;
    uint4 v = *reinterpret_cast<const uint4*>(src + ((long)(g * 512 + hbase + dd)) * 512 + chunk * 8);
    *reinterpret_cast<uint4*>(&w_lds[row][chunk * 8]) = v;
  }
  __syncthreads();

  int mt = wave & 1, nt = wave >> 1;
  bool mact = (nt * 16) < NPAD;
  int colw = nt * 16 + (lane & 15);
  int wr = (colw < NG * 8) ? colw : (NG * 8 - 1);   // clamped B row (cols>=NG*8 unused)
  int arow = mt * 16 + (lane & 15);
  int kq = (lane >> 4) * 8;
  int quad = lane >> 4;
  float Gw = 0.f, bxc = 0.f, bhw = 0.f;
  if (mact && colw < NG * 8) {
    int g = colw >> 3, dd = colw & 7;
    int n = g * 512 + hbase + dd;
    if constexpr (ROLE == 1) { Gw = Gn[n]; bxc = Bn[n] + bih[n]; bhw = bhh[n]; }
    if constexpr (ROLE == 2) { Gw = Gn[n]; bxc = Bn[n] + bih[n] + bhh[n]; }
    (void)g;
  }
  int b_c = tid >> 3, d_c = tid & 7;   // cell thread owns h[b_c][hbase+d_c]
  float c_st = 0.f, h_st = 0.f;

  for (int t = 0; t < T_SEQ; ++t) {
    u64 xq = 0;
    if constexpr (ROLE == 0)
      xq = *reinterpret_cast<const u64*>(xg + (((long)t * BATCH + b_c) * HID + hbase + d_c) * 4);

    if (mact) {
      float s = 0.f, s2 = 0.f, dummy = 0.f;
      f32x4 aX = {0.f,0.f,0.f,0.f}, aH = {0.f,0.f,0.f,0.f};
      if constexpr (ROLE > 0) {
        // wait for full upstream h(t), then issue aX loads (stats ride along)
        while (true) {
          int f = ld_flag(&fl_up[lane]);
          if (__all(f >= t + 1)) break;
          __builtin_amdgcn_s_sleep(1);
        }
        __asm__ volatile("" ::: "memory");
        aX = frag_gemm<true>(up + ((long)(t & (RING - 1)) * BATCH + arow) * HID + kq,
                             kq, w_lds, wr, s, s2);
      }
      if (t > 0) {
        // own-h flags usually already set; aX loads still in flight here
        while (true) {
          int f = ld_flag(&fl_own[lane]);
          if (__all(f >= t)) break;
          __builtin_amdgcn_s_sleep(1);
        }
        __asm__ volatile("" ::: "memory");
        aH = frag_gemm<false>(hist + ((long)((t - 1) & (RH - 1)) * BATCH + arow) * HID + kq,
                              kq, w_lds + XROWS, wr, dummy, dummy);
      }
      if constexpr (ROLE > 0) {
        // complete row stats across the 4 column groups (lanes xor 16, 32)
        s  += __shfl_xor(s, 16);  s  += __shfl_xor(s, 32);
        s2 += __shfl_xor(s2, 16); s2 += __shfl_xor(s2, 32);
        float mu = s * (1.f / 512.f);
        float var = s2 * (1.f / 512.f) - mu * mu;
        float rs = rsqrtf(var + 1e-5f);
        float rmu = rs * mu;
#pragma unroll
        for (int r = 0; r < 4; ++r) {
          int row = mt * 16 + quad * 4 + r;
          float rr  = __shfl(rs,  quad * 4 + r);
          float rmr = __shfl(rmu, quad * 4 + r);
          gx[row][colw] = rr * aX[r] - rmr * Gw + bxc;
          gh[row][colw] = aH[r] + bhw;
        }
      } else {
#pragma unroll
        for (int r = 0; r < 4; ++r) {
          int row = mt * 16 + quad * 4 + r;
          gh[row][colw] = aH[r];
        }
      }
    }
    __syncthreads();

    // ---- cell ----
    float hnew;
    if constexpr (ROLE == 0) {
      float xv0 = bf2f((u16)(xq));
      float xv1 = bf2f((u16)(xq >> 16));
      float xv2 = bf2f((u16)(xq >> 32));
      float xv3 = bf2f((u16)(xq >> 48));
      float h0 = gh[b_c][0 * 8 + d_c];
      float h1 = gh[b_c][1 * 8 + d_c];
      float h2 = gh[b_c][2 * 8 + d_c];
      float h3 = gh[b_c][3 * 8 + d_c];
      float ig = sigf(xv0 + h0), fg = sigf(xv1 + h1);
      float gg = tanh_fast(xv2 + h2), og = sigf(xv3 + h3);
      c_st = fg * c_st + ig * gg;
      hnew = og * tanh_fast(c_st);
    } else if constexpr (ROLE == 1) {
      float xr_ = gx[b_c][0 * 8 + d_c], xz = gx[b_c][1 * 8 + d_c], xn = gx[b_c][2 * 8 + d_c];
      float hr  = gh[b_c][0 * 8 + d_c], hz = gh[b_c][1 * 8 + d_c], hn = gh[b_c][2 * 8 + d_c];
      float r = sigf(xr_ + hr), z = sigf(xz + hz);
      float n = tanh_fast(xn + r * hn);
      hnew = (1.f - z) * n + z * h_st;
      h_st = hnew;
    } else {
      hnew = tanh_fast(gx[b_c][d_c] + gh[b_c][d_c]);
    }
    hs[b_c][d_c] = f2bf(hnew);
    __syncthreads();

    // ---- publish (wave0) ----
    if (wave == 0) {
      if (cons != nullptr && t >= RH) {   // ring back-pressure (rarely binds)
        int tgt = t - RH + 1;
        while (true) {
          int f = ld_flag(&cons[lane]);
          if (__all(f >= tgt)) break;
          __builtin_amdgcn_s_sleep(1);
        }
      }
      int pb = lane >> 1, half = lane & 1;
      u64 val = *reinterpret_cast<const u64*>(&hs[pb][half * 4]);
      st_dev(reinterpret_cast<u64*>(hist + ((long)(t & (RH - 1)) * BATCH + pb) * HID + hbase + half * 4), val);
      __asm__ volatile("s_waitcnt vmcnt(0)" ::: "memory");
      if (tid == 0)
        __hip_atomic_store(&fl_own[wg], t + 1, __ATOMIC_RELAXED, __HIP_MEMORY_SCOPE_AGENT);
    }
  }
}

// ---------------- fused pipeline kernel: 192 WGs ----------------
// flags: [0..63] lstm, [64..127] gru, [128..191] rnn
__global__ __launch_bounds__(256) void fused_kernel(
    const u16* __restrict__ xg, const u16* __restrict__ lstm_whh,
    const u16* __restrict__ gru_wih, const u16* __restrict__ gru_whh,
    const float* __restrict__ gru_bih, const float* __restrict__ gru_bhh,
    const float* __restrict__ G1, const float* __restrict__ B1,
    const u16* __restrict__ rnn_wih, const u16* __restrict__ rnn_whh,
    const float* __restrict__ rnn_bih, const float* __restrict__ rnn_bhh,
    const float* __restrict__ G2, const float* __restrict__ B2,
    u16* h1, u16* h2, u16* h3, int* fl)
{
  __shared__ u16 w_lds[48][520];     // 49.9 KB  (total static ~58.9 KB < 64 KB)
  __shared__ float gx[32][33];       // 4.2 KB
  __shared__ float gh[32][33];       // 4.2 KB
  __shared__ u16 hs[32][8];          // 0.5 KB
  int bid = blockIdx.x;
  if (bid < 64)
    recur_role<0>(bid, xg, nullptr, nullptr, lstm_whh, nullptr, nullptr, nullptr, nullptr,
                  h1, nullptr, fl + 0, fl + 64, w_lds, gx, gh, hs);
  else if (bid < 128)
    recur_role<1>(bid - 64, nullptr, h1, gru_wih, gru_whh, gru_bih, gru_bhh, G1, B1,
                  h2, fl + 0, fl + 64, fl + 128, w_lds, gx, gh, hs);
  else
    recur_role<2>(bid - 128, nullptr, h2, rnn_wih, rnn_whh, rnn_bih, rnn_bhh, G2, B2,
                  h3, fl + 64, fl + 128, nullptr, w_lds, gx, gh, hs);
}

// ---------------- final FC ----------------
__global__ __launch_bounds__(256) void fc_kernel(
    const u16* __restrict__ hlast, const u16* __restrict__ w,
    const float* __restrict__ bias, float* __restrict__ out)
{
  int tg = blockIdx.x * 256 + threadIdx.x;
  if (tg >= BATCH * 1000) return;
  int b = tg / 1000, o = tg % 1000;
  const u16* hp = hlast + (long)b * HID;
  const u16* wp = w + (long)o * HID;
  float acc = 0.f;
  for (int k = 0; k < HID; k += 8) {
    uint4 hu = *reinterpret_cast<const uint4*>(hp + k);
    uint4 wu = *reinterpret_cast<const uint4*>(wp + k);
    u16* hsv = reinterpret_cast<u16*>(&hu);
    u16* wsv = reinterpret_cast<u16*>(&wu);
#pragma unroll
    for (int i = 0; i < 8; ++i) acc += bf2f(hsv[i]) * bf2f(wsv[i]);
  }
  out[tg] = acc + bias[o];
}

__global__ void sentinel_kernel(float* out) { out[0] = 12345.0f; }

// ---------------- launch ----------------
extern "C" void kernel_launch(void* const* d_in, const int* in_sizes, int n_in,
                              void* d_out, int out_size, void* d_ws, size_t ws_size,
                              hipStream_t stream)
{
  (void)in_sizes; (void)n_in; (void)out_size;
  const float* x        = (const float*)d_in[0];
  const float* lstm_wih = (const float*)d_in[1];
  const float* lstm_whh = (const float*)d_in[2];
  const float* lstm_bih = (const float*)d_in[3];
  const float* lstm_bhh = (const float*)d_in[4];
  const float* ln1_g    = (const float*)d_in[5];
  const float* ln1_b    = (const float*)d_in[6];
  const float* gru_wih  = (const float*)d_in[7];
  const float* gru_whh  = (const float*)d_in[8];
  const float* gru_bih  = (const float*)d_in[9];
  const float* gru_bhh  = (const float*)d_in[10];
  const float* ln2_g    = (const float*)d_in[11];
  const float* ln2_b    = (const float*)d_in[12];
  const float* rnn_wih  = (const float*)d_in[13];
  const float* rnn_whh  = (const float*)d_in[14];
  const float* rnn_bih  = (const float*)d_in[15];
  const float* rnn_bhh  = (const float*)d_in[16];
  const float* fc_w     = (const float*)d_in[17];
  const float* fc_b     = (const float*)d_in[18];
  float* out = (float*)d_out;

  char* ws = (char*)d_ws;
  size_t off = 0;
  auto alloc = [&](size_t bytes) -> void* {
    void* p = ws + off; off += (bytes + 255) & ~(size_t)255; return p;
  };
  int* flags     = (int*)alloc(192 * sizeof(int));
  u16* xbf       = (u16*)alloc((size_t)BATCH * T_SEQ * 256 * 2);
  u16* lstm_wih_b= (u16*)alloc((size_t)2048 * 256 * 2);
  u16* lstm_whh_b= (u16*)alloc((size_t)2048 * 512 * 2);
  u16* gru_wih_b = (u16*)alloc((size_t)1536 * 512 * 2);
  u16* gru_whh_b = (u16*)alloc((size_t)1536 * 512 * 2);
  u16* rnn_wih_b = (u16*)alloc((size_t)512 * 512 * 2);
  u16* rnn_whh_b = (u16*)alloc((size_t)512 * 512 * 2);
  u16* fc_w_b    = (u16*)alloc((size_t)1000 * 512 * 2);
  float* G1      = (float*)alloc(1536 * sizeof(float));
  float* B1      = (float*)alloc(1536 * sizeof(float));
  float* G2      = (float*)alloc(512 * sizeof(float));
  float* B2      = (float*)alloc(512 * sizeof(float));
  u16* xg2       = (u16*)alloc((size_t)T_SEQ * BATCH * HID * 4 * 2);  // 128 MB
  u16* h1        = (u16*)alloc((size_t)RING * BATCH * HID * 2);       // 1 MB rings
  u16* h2        = (u16*)alloc((size_t)RING * BATCH * HID * 2);
  u16* h3        = (u16*)alloc((size_t)2 * BATCH * HID * 2);          // ping-pong

  if (off > ws_size) {
    sentinel_kernel<<<1, 1, 0, stream>>>(out);
    return;
  }

  hipMemsetAsync(flags, 0, 192 * sizeof(int), stream);

  auto cast = [&](const float* src, u16* dst, int n) {
    cast_f32_bf16<<<(n + 2047) / 2048, 256, 0, stream>>>(src, dst, n);
  };
  cast(x,        xbf,        BATCH * T_SEQ * 256);
  cast(lstm_wih, lstm_wih_b, 2048 * 256);
  cast(lstm_whh, lstm_whh_b, 2048 * 512);
  cast(gru_whh,  gru_whh_b,  1536 * 512);
  cast(rnn_whh,  rnn_whh_b,  512 * 512);
  cast(fc_w,     fc_w_b,     1000 * 512);

  // LN-folded input weights: W' = bf16(W ∘ g), Gn = Σ g*W, Bn = Σ b*W
  prep_wih<<<1536 / 4, 256, 0, stream>>>(gru_wih, ln1_g, ln1_b, gru_wih_b, G1, B1, 1536);
  prep_wih<<<512 / 4, 256, 0, stream>>>(rnn_wih, ln2_g, ln2_b, rnn_wih_b, G2, B2, 512);

  const int M64 = (BATCH * T_SEQ) / 64;  // 512
  gemm_xg<<<dim3(M64, 2048 / 64), 256, 0, stream>>>(
      xbf, lstm_wih_b, lstm_bih, lstm_bhh, xg2, 2048, 256, 1024, 1);

  fused_kernel<<<192, 256, 0, stream>>>(
      xg2, lstm_whh_b,
      gru_wih_b, gru_whh_b, gru_bih, gru_bhh, G1, B1,
      rnn_wih_b, rnn_whh_b, rnn_bih, rnn_bhh, G2, B2,
      h1, h2, h3, flags);

  // h3 last written slot = (T_SEQ-1)&1 = 1
  fc_kernel<<<(BATCH * 1000 + 255) / 256, 256, 0, stream>>>(
      h3 + (size_t)BATCH * HID, fc_w_b, fc_b, out);
}

// Round 8
// 11280.659 us; speedup vs baseline: 1.3660x; 1.0085x over previous
//
#include <hip/hip_runtime.h>
#include <stdint.h>

#define T_SEQ 1024
#define BATCH 32
#define HID   512
#define RING  32     // inter-stage ring depth (power of 2)
#define NWGR  32     // recurrent WGs per layer (16 h-units each)

typedef unsigned short u16;
typedef unsigned long long u64;
typedef short bf16x8 __attribute__((ext_vector_type(8)));
typedef float f32x4  __attribute__((ext_vector_type(4)));

__device__ __forceinline__ float bf2f(u16 u) {
  union { unsigned u; float f; } v; v.u = ((unsigned)u) << 16; return v.f;
}
__device__ __forceinline__ u16 f2bf(float f) {
  union { float f; unsigned u; } v; v.f = f;
  unsigned r = v.u + 0x7fffu + ((v.u >> 16) & 1u);   // RNE
  return (u16)(r >> 16);
}
__device__ __forceinline__ float sigf(float x) { return 1.0f / (1.0f + __expf(-x)); }
__device__ __forceinline__ float tanh_fast(float x) { return 2.0f * sigf(2.0f * x) - 1.0f; }

// Device-scope coherent 8B load/store: bypass stale per-XCD L2, no wbl2/inv.
__device__ __forceinline__ u64 ld_dev(const u64* p) {
  return __hip_atomic_load(p, __ATOMIC_RELAXED, __HIP_MEMORY_SCOPE_AGENT);
}
__device__ __forceinline__ void st_dev(u64* p, u64 v) {
  __hip_atomic_store(p, v, __ATOMIC_RELAXED, __HIP_MEMORY_SCOPE_AGENT);
}
__device__ __forceinline__ int ld_flag(const int* p) {
  return __hip_atomic_load(p, __ATOMIC_RELAXED, __HIP_MEMORY_SCOPE_AGENT);
}

// ---------------- cast fp32 -> bf16 ----------------
__global__ __launch_bounds__(256) void cast_f32_bf16(const float* __restrict__ in,
                                                     u16* __restrict__ out, int n) {
  int i = (blockIdx.x * 256 + threadIdx.x) * 8;
  if (i + 7 < n) {
    float4 v0 = *reinterpret_cast<const float4*>(in + i);
    float4 v1 = *reinterpret_cast<const float4*>(in + i + 4);
    uint4 o;
    o.x = (unsigned)f2bf(v0.x) | ((unsigned)f2bf(v0.y) << 16);
    o.y = (unsigned)f2bf(v0.z) | ((unsigned)f2bf(v0.w) << 16);
    o.z = (unsigned)f2bf(v1.x) | ((unsigned)f2bf(v1.y) << 16);
    o.w = (unsigned)f2bf(v1.z) | ((unsigned)f2bf(v1.w) << 16);
    *reinterpret_cast<uint4*>(out + i) = o;
  } else {
    for (; i < n; ++i) out[i] = f2bf(in[i]);
  }
}

// ---------------- LSTM input GEMM: out[t][b][k][g] = x @ w_ih^T + b_ih + b_hh ----------------
__global__ __launch_bounds__(256) void gemm_xg(
    const u16* __restrict__ A, const u16* __restrict__ W,
    const float* __restrict__ bias1, const float* __restrict__ bias2,
    u16* __restrict__ out, int N, int K, int strideB, int strideT)
{
  __shared__ u16 As[64][72];
  __shared__ u16 Bs[64][72];
  int tid  = threadIdx.x;
  int lane = tid & 63;
  int wave = tid >> 6;
  int m0 = blockIdx.x * 64;
  int n0 = blockIdx.y * 64;

  f32x4 zero = {0.f, 0.f, 0.f, 0.f};
  f32x4 acc[4] = {zero, zero, zero, zero};

  int srow = tid >> 2;
  int scol = (tid & 3) * 16;

  int m_s = m0 + srow;
  long arow = (long)(m_s & (BATCH - 1)) * strideB + (long)(m_s >> 5) * strideT;
  const u16* aptr = A + arow * K + scol;
  const u16* wptr = W + (long)(n0 + srow) * K + scol;

  for (int kk = 0; kk < K; kk += 64) {
    __syncthreads();
    uint4 a0 = *reinterpret_cast<const uint4*>(aptr + kk);
    uint4 a1 = *reinterpret_cast<const uint4*>(aptr + kk + 8);
    uint4 b0 = *reinterpret_cast<const uint4*>(wptr + kk);
    uint4 b1 = *reinterpret_cast<const uint4*>(wptr + kk + 8);
    *reinterpret_cast<uint4*>(&As[srow][scol])     = a0;
    *reinterpret_cast<uint4*>(&As[srow][scol + 8]) = a1;
    *reinterpret_cast<uint4*>(&Bs[srow][scol])     = b0;
    *reinterpret_cast<uint4*>(&Bs[srow][scol + 8]) = b1;
    __syncthreads();
    int am = wave * 16 + (lane & 15);
    int kq = (lane >> 4) * 8;
#pragma unroll
    for (int ks = 0; ks < 2; ++ks) {
      bf16x8 af = *reinterpret_cast<const bf16x8*>(&As[am][kq + ks * 32]);
#pragma unroll
      for (int nb = 0; nb < 4; ++nb) {
        bf16x8 bf = *reinterpret_cast<const bf16x8*>(&Bs[nb * 16 + (lane & 15)][kq + ks * 32]);
        acc[nb] = __builtin_amdgcn_mfma_f32_16x16x32_bf16(af, bf, acc[nb], 0, 0, 0);
      }
    }
  }
  int quad = lane >> 4;
#pragma unroll
  for (int nb = 0; nb < 4; ++nb) {
    int n = n0 + nb * 16 + (lane & 15);
    float bv = bias1[n] + (bias2 ? bias2[n] : 0.0f);
    int g = n >> 9, k = n & 511;
#pragma unroll
    for (int r = 0; r < 4; ++r) {
      int m = m0 + wave * 16 + quad * 4 + r;
      int t = m >> 5, b = m & (BATCH - 1);
      out[(((long)t * BATCH + b) * HID + k) * 4 + g] = f2bf(acc[nb][r] + bv);
    }
  }
}

// 16x16x32 K=512 tile from pre-loaded A registers + LDS B.
__device__ __forceinline__ f32x4 tile_mm(const u64* A, const u16 (*w)[520], int wrow, int kq) {
  f32x4 a0 = {0.f,0.f,0.f,0.f}, a1 = {0.f,0.f,0.f,0.f};
#pragma unroll
  for (int ks = 0; ks < 16; ++ks) {
    union { u64 q[2]; bf16x8 v; } c;
    c.q[0] = A[2 * ks]; c.q[1] = A[2 * ks + 1];
    bf16x8 bv = *reinterpret_cast<const bf16x8*>(&w[wrow][kq + ks * 32]);
    if (ks & 1) a1 = __builtin_amdgcn_mfma_f32_16x16x32_bf16(c.v, bv, a1, 0, 0, 0);
    else        a0 = __builtin_amdgcn_mfma_f32_16x16x32_bf16(c.v, bv, a0, 0, 0, 0);
  }
  return a0 + a1;
}

// ---------------- persistent recurrent role (ROLE: 0=LSTM 1=GRU 2=RNN) ----------------
// 32 WGs/layer, 16 h-units each; tile index == gate index (16 units/gate/WG).
template <int ROLE>
__device__ void recur_role(
    int wg, const u16* __restrict__ xg, const u16* __restrict__ up,
    const u16* __restrict__ wih, const u16* __restrict__ whh,
    const float* __restrict__ bih, const float* __restrict__ bhh,
    u16* __restrict__ hist, const int* fl_up, int n_up, int* fl_own,
    const int* cons, int n_cons,
    u16 (*w_lds)[520], float (*gx)[66], float (*gh)[66], u16 (*hs)[16])
{
  constexpr int NG = (ROLE == 0) ? 4 : (ROLE == 1) ? 3 : 1;
  constexpr int NCOLS = NG * 16;
  constexpr int NT = NG;                     // 16-wide tiles == gates
  constexpr int XROWS = (ROLE > 0) ? NCOLS : 0;
  constexpr int TOT = XROWS + NCOLS;
  constexpr int RH = (ROLE == 2) ? 2 : RING;
  int tid = threadIdx.x, lane = tid & 63, wave = tid >> 6;
  int hbase = wg * 16;

  // stage weights: rows [0,XROWS) = W_ih slice, [XROWS,TOT) = W_hh slice
  for (int idx = tid; idx < TOT * 64; idx += 256) {
    int row = idx >> 6, chunk = idx & 63;
    int n = (row < XROWS) ? row : (row - XROWS);
    const u16* src = (row < XROWS) ? wih : whh;
    int g = n >> 4, dd = n & 15;
    uint4 v = *reinterpret_cast<const uint4*>(src + ((long)(g * 512 + hbase + dd)) * 512 + chunk * 8);
    *reinterpret_cast<uint4*>(&w_lds[row][chunk * 8]) = v;
  }
  __syncthreads();

  int mt = wave & 1;           // M half (batch rows)
  int nt0 = wave >> 1;         // first column tile
  int ncnt = (NT > nt0) ? ((NT - nt0 + 1) >> 1) : 0;
  bool mact = ncnt > 0;
  int arow = mt * 16 + (lane & 15);
  int kq = (lane >> 4) * 8;
  int quad = lane >> 4;

  float bx[2] = {0.f, 0.f}, bh2[2] = {0.f, 0.f};
#pragma unroll
  for (int j = 0; j < 2; ++j) {
    int nt = nt0 + 2 * j;
    if (nt < NT) {
      int n = nt * 512 + hbase + (lane & 15);
      if constexpr (ROLE == 1) { bx[j] = bih[n]; bh2[j] = bhh[n]; }
      if constexpr (ROLE == 2) { bx[j] = bih[n] + bhh[n]; }
      (void)n;
    }
  }

  int b_c = tid >> 3, d0 = tid & 7;      // cell thread: rows b_c, units d0 and d0+8
  float cA = 0.f, cB = 0.f;              // LSTM cell states (2 units)
  float hA = 0.f, hB = 0.f;              // GRU prev h (2 units)

  for (int t = 0; t < T_SEQ; ++t) {
    u64 xq0 = 0, xq1 = 0;
    if constexpr (ROLE == 0) {
      const u16* xp = xg + (((long)t * BATCH + b_c) * HID + hbase) * 4;
      xq0 = *reinterpret_cast<const u64*>(xp + d0 * 4);
      xq1 = *reinterpret_cast<const u64*>(xp + (d0 + 8) * 4);
    }

    u64 Aup[32], Aown[32];
    if (mact) {
      if constexpr (ROLE > 0) {
        while (true) {
          int f = t + 1;
          if (lane < n_up) f = ld_flag(&fl_up[lane]);
          if (__all(f >= t + 1)) break;
          __builtin_amdgcn_s_sleep(1);
        }
        __asm__ volatile("" ::: "memory");
        const u64* p = reinterpret_cast<const u64*>(
            up + ((long)(t & (RING - 1)) * BATCH + arow) * HID + kq);
#pragma unroll
        for (int i = 0; i < 16; ++i) { Aup[2*i] = ld_dev(p + i*8); Aup[2*i+1] = ld_dev(p + i*8 + 1); }
      }
      if (t > 0) {
        while (true) {
          int f = t;
          if (lane < NWGR) f = ld_flag(&fl_own[lane]);
          if (__all(f >= t)) break;
          __builtin_amdgcn_s_sleep(1);
        }
        __asm__ volatile("" ::: "memory");
        const u64* p = reinterpret_cast<const u64*>(
            hist + ((long)((t - 1) & (RH - 1)) * BATCH + arow) * HID + kq);
#pragma unroll
        for (int i = 0; i < 16; ++i) { Aown[2*i] = ld_dev(p + i*8); Aown[2*i+1] = ld_dev(p + i*8 + 1); }
      }
#pragma unroll
      for (int j = 0; j < 2; ++j) {
        int nt = nt0 + 2 * j;
        if (nt >= NT) break;
        int colw = nt * 16 + (lane & 15);
        f32x4 aX = {0.f,0.f,0.f,0.f}, aH = {0.f,0.f,0.f,0.f};
        if constexpr (ROLE > 0) aX = tile_mm(Aup, w_lds, colw, kq);
        if (t > 0)              aH = tile_mm(Aown, w_lds + XROWS, colw, kq);
#pragma unroll
        for (int r = 0; r < 4; ++r) {
          int row = mt * 16 + quad * 4 + r;
          if constexpr (ROLE > 0) gx[row][colw] = aX[r] + bx[j];
          gh[row][colw] = aH[r] + bh2[j];
        }
      }
    }
    __syncthreads();

    // ---- cell: 2 units per thread ----
    if constexpr (ROLE == 0) {
      float c_prev[2] = {cA, cB};
      u64 xqv[2] = {xq0, xq1};
#pragma unroll
      for (int k = 0; k < 2; ++k) {
        int u = d0 + 8 * k;
        float xv0 = bf2f((u16)(xqv[k]));
        float xv1 = bf2f((u16)(xqv[k] >> 16));
        float xv2 = bf2f((u16)(xqv[k] >> 32));
        float xv3 = bf2f((u16)(xqv[k] >> 48));
        float ig = sigf(xv0 + gh[b_c][u]);
        float fg = sigf(xv1 + gh[b_c][16 + u]);
        float gg = tanh_fast(xv2 + gh[b_c][32 + u]);
        float og = sigf(xv3 + gh[b_c][48 + u]);
        float c = fg * c_prev[k] + ig * gg;
        c_prev[k] = c;
        hs[b_c][u] = f2bf(og * tanh_fast(c));
      }
      cA = c_prev[0]; cB = c_prev[1];
    } else if constexpr (ROLE == 1) {
      float h_prev[2] = {hA, hB};
#pragma unroll
      for (int k = 0; k < 2; ++k) {
        int u = d0 + 8 * k;
        float r = sigf(gx[b_c][u] + gh[b_c][u]);
        float z = sigf(gx[b_c][16 + u] + gh[b_c][16 + u]);
        float n = tanh_fast(gx[b_c][32 + u] + r * gh[b_c][32 + u]);
        float hn = (1.f - z) * n + z * h_prev[k];
        h_prev[k] = hn;
        hs[b_c][u] = f2bf(hn);
      }
      hA = h_prev[0]; hB = h_prev[1];
    } else {
#pragma unroll
      for (int k = 0; k < 2; ++k) {
        int u = d0 + 8 * k;
        hs[b_c][u] = f2bf(tanh_fast(gx[b_c][u] + gh[b_c][u]));
      }
    }
    __syncthreads();

    // ---- publish (wave0): 32 rows x 32B ----
    if (wave == 0) {
      if (cons != nullptr && t >= RING) {     // ring back-pressure (rarely binds)
        int tgt = t - RING + 1;
        while (true) {
          int f = tgt;
          if (lane < n_cons) f = ld_flag(&cons[lane]);
          if (__all(f >= tgt)) break;
          __builtin_amdgcn_s_sleep(1);
        }
      }
      int row = lane >> 1, half = lane & 1;
      u64 v0 = *reinterpret_cast<const u64*>(&hs[row][half * 8]);
      u64 v1 = *reinterpret_cast<const u64*>(&hs[row][half * 8 + 4]);
      u64* hp = reinterpret_cast<u64*>(
          hist + ((long)(t & (RH - 1)) * BATCH + row) * HID + hbase + half * 8);
      st_dev(hp, v0);
      st_dev(hp + 1, v1);
      __asm__ volatile("s_waitcnt vmcnt(0)" ::: "memory");
      if (tid == 0)
        __hip_atomic_store(&fl_own[wg], t + 1, __ATOMIC_RELAXED, __HIP_MEMORY_SCOPE_AGENT);
    }
  }
}

// ---------------- pipelined LayerNorm role (4 WGs x 8 rows) ----------------
__device__ void ln_role(int wg, const u16* __restrict__ in, u16* __restrict__ out,
                        const float* __restrict__ gv, const float* __restrict__ bv,
                        const int* fl_in, int n_in, int* fl_out,
                        const int* cons, int n_cons)
{
  int tid = threadIdx.x, lane = tid & 63, wave = tid >> 6;
  int row = wg * 8 + wave * 2 + (lane >> 5);
  int l32 = lane & 31, k0 = l32 * 16;
  float gr[16], br[16];
#pragma unroll
  for (int j = 0; j < 16; ++j) { gr[j] = gv[k0 + j]; br[j] = bv[k0 + j]; }

  for (int t = 0; t < T_SEQ; ++t) {
    while (true) {
      int f = t + 1;
      if (lane < n_in) f = ld_flag(&fl_in[lane]);
      if (__all(f >= t + 1)) break;
      __builtin_amdgcn_s_sleep(1);
    }
    if (t >= RING) {
      int tg2 = t - RING + 1;
      while (true) {
        int f = tg2;
        if (lane < n_cons) f = ld_flag(&cons[lane]);
        if (__all(f >= tg2)) break;
        __builtin_amdgcn_s_sleep(1);
      }
    }
    __asm__ volatile("" ::: "memory");
    const u64* p = reinterpret_cast<const u64*>(in + ((long)(t & (RING - 1)) * BATCH + row) * HID + k0);
    u64 q[4];
#pragma unroll
    for (int i = 0; i < 4; ++i) q[i] = ld_dev(p + i);
    float x[16];
#pragma unroll
    for (int i = 0; i < 16; ++i) x[i] = bf2f((u16)(q[i >> 2] >> (16 * (i & 3))));
    float s = 0.f, s2 = 0.f;
#pragma unroll
    for (int i = 0; i < 16; ++i) { s += x[i]; s2 += x[i] * x[i]; }
#pragma unroll
    for (int off = 1; off < 32; off <<= 1) { s += __shfl_xor(s, off); s2 += __shfl_xor(s2, off); }
    float mu = s * (1.f / 512.f);
    float var = s2 * (1.f / 512.f) - mu * mu;
    float rs = rsqrtf(var + 1e-5f);
    u16 o[16];
#pragma unroll
    for (int i = 0; i < 16; ++i) o[i] = f2bf((x[i] - mu) * rs * gr[i] + br[i]);
    u64* po = reinterpret_cast<u64*>(out + ((long)(t & (RING - 1)) * BATCH + row) * HID + k0);
    const u64* oq = reinterpret_cast<const u64*>(o);
#pragma unroll
    for (int i = 0; i < 4; ++i) st_dev(po + i, oq[i]);
    __asm__ volatile("s_waitcnt vmcnt(0)" ::: "memory");
    __syncthreads();
    if (tid == 0)
      __hip_atomic_store(&fl_out[wg], t + 1, __ATOMIC_RELAXED, __HIP_MEMORY_SCOPE_AGENT);
  }
}

// dynamic LDS carve (bytes)
#define SM_W    0                         // 96 x 520 x 2 = 99840
#define SM_GX   99840                     // 32 x 66 x 4  = 8448
#define SM_GH   108288                    // 8448
#define SM_HS   116736                    // 32 x 16 x 2  = 1024
#define SM_TOT  117760

// ---------------- fused pipeline kernel: 104 WGs, 1 WG/CU ----------------
// flags: [0..31] lstm, [32..35] ln1, [64..95] gru, [96..99] ln2, [128..159] rnn
__global__ __launch_bounds__(256, 1) void fused_kernel(
    const u16* __restrict__ xg, const u16* __restrict__ lstm_whh,
    const u16* __restrict__ gru_wih, const u16* __restrict__ gru_whh,
    const float* __restrict__ gru_bih, const float* __restrict__ gru_bhh,
    const u16* __restrict__ rnn_wih, const u16* __restrict__ rnn_whh,
    const float* __restrict__ rnn_bih, const float* __restrict__ rnn_bhh,
    const float* __restrict__ ln1_g, const float* __restrict__ ln1_b,
    const float* __restrict__ ln2_g, const float* __restrict__ ln2_b,
    u16* h1, u16* ln1o, u16* h2, u16* ln2o, u16* h3, int* fl)
{
  extern __shared__ char smem[];
  u16 (*w_lds)[520] = reinterpret_cast<u16(*)[520]>(smem + SM_W);
  float (*gx)[66]   = reinterpret_cast<float(*)[66]>(smem + SM_GX);
  float (*gh)[66]   = reinterpret_cast<float(*)[66]>(smem + SM_GH);
  u16 (*hs)[16]     = reinterpret_cast<u16(*)[16]>(smem + SM_HS);
  int bid = blockIdx.x;
  if (bid < 32)
    recur_role<0>(bid, xg, nullptr, nullptr, lstm_whh, nullptr, nullptr,
                  h1, nullptr, 0, fl + 0, fl + 32, 4, w_lds, gx, gh, hs);
  else if (bid < 36)
    ln_role(bid - 32, h1, ln1o, ln1_g, ln1_b, fl + 0, 32, fl + 32, fl + 64, 32);
  else if (bid < 68)
    recur_role<1>(bid - 36, nullptr, ln1o, gru_wih, gru_whh, gru_bih, gru_bhh,
                  h2, fl + 32, 4, fl + 64, fl + 96, 4, w_lds, gx, gh, hs);
  else if (bid < 72)
    ln_role(bid - 68, h2, ln2o, ln2_g, ln2_b, fl + 64, 32, fl + 96, fl + 128, 32);
  else
    recur_role<2>(bid - 72, nullptr, ln2o, rnn_wih, rnn_whh, rnn_bih, rnn_bhh,
                  h3, fl + 96, 4, fl + 128, nullptr, 0, w_lds, gx, gh, hs);
}

// ---------------- final FC ----------------
__global__ __launch_bounds__(256) void fc_kernel(
    const u16* __restrict__ hlast, const u16* __restrict__ w,
    const float* __restrict__ bias, float* __restrict__ out)
{
  int tg = blockIdx.x * 256 + threadIdx.x;
  if (tg >= BATCH * 1000) return;
  int b = tg / 1000, o = tg % 1000;
  const u16* hp = hlast + (long)b * HID;
  const u16* wp = w + (long)o * HID;
  float acc = 0.f;
  for (int k = 0; k < HID; k += 8) {
    uint4 hu = *reinterpret_cast<const uint4*>(hp + k);
    uint4 wu = *reinterpret_cast<const uint4*>(wp + k);
    u16* hsv = reinterpret_cast<u16*>(&hu);
    u16* wsv = reinterpret_cast<u16*>(&wu);
#pragma unroll
    for (int i = 0; i < 8; ++i) acc += bf2f(hsv[i]) * bf2f(wsv[i]);
  }
  out[tg] = acc + bias[o];
}

__global__ void sentinel_kernel(float* out) { out[0] = 12345.0f; }

// ---------------- launch ----------------
extern "C" void kernel_launch(void* const* d_in, const int* in_sizes, int n_in,
                              void* d_out, int out_size, void* d_ws, size_t ws_size,
                              hipStream_t stream)
{
  (void)in_sizes; (void)n_in; (void)out_size;
  const float* x        = (const float*)d_in[0];
  const float* lstm_wih = (const float*)d_in[1];
  const float* lstm_whh = (const float*)d_in[2];
  const float* lstm_bih = (const float*)d_in[3];
  const float* lstm_bhh = (const float*)d_in[4];
  const float* ln1_g    = (const float*)d_in[5];
  const float* ln1_b    = (const float*)d_in[6];
  const float* gru_wih  = (const float*)d_in[7];
  const float* gru_whh  = (const float*)d_in[8];
  const float* gru_bih  = (const float*)d_in[9];
  const float* gru_bhh  = (const float*)d_in[10];
  const float* ln2_g    = (const float*)d_in[11];
  const float* ln2_b    = (const float*)d_in[12];
  const float* rnn_wih  = (const float*)d_in[13];
  const float* rnn_whh  = (const float*)d_in[14];
  const float* rnn_bih  = (const float*)d_in[15];
  const float* rnn_bhh  = (const float*)d_in[16];
  const float* fc_w     = (const float*)d_in[17];
  const float* fc_b     = (const float*)d_in[18];
  float* out = (float*)d_out;

  char* ws = (char*)d_ws;
  size_t off = 0;
  auto alloc = [&](size_t bytes) -> void* {
    void* p = ws + off; off += (bytes + 255) & ~(size_t)255; return p;
  };
  int* flags     = (int*)alloc(160 * sizeof(int));
  u16* xbf       = (u16*)alloc((size_t)BATCH * T_SEQ * 256 * 2);
  u16* lstm_wih_b= (u16*)alloc((size_t)2048 * 256 * 2);
  u16* lstm_whh_b= (u16*)alloc((size_t)2048 * 512 * 2);
  u16* gru_wih_b = (u16*)alloc((size_t)1536 * 512 * 2);
  u16* gru_whh_b = (u16*)alloc((size_t)1536 * 512 * 2);
  u16* rnn_wih_b = (u16*)alloc((size_t)512 * 512 * 2);
  u16* rnn_whh_b = (u16*)alloc((size_t)512 * 512 * 2);
  u16* fc_w_b    = (u16*)alloc((size_t)1000 * 512 * 2);
  u16* xg2       = (u16*)alloc((size_t)T_SEQ * BATCH * HID * 4 * 2);  // 128 MB
  u16* h1        = (u16*)alloc((size_t)RING * BATCH * HID * 2);       // 1 MB rings
  u16* ln1o      = (u16*)alloc((size_t)RING * BATCH * HID * 2);
  u16* h2        = (u16*)alloc((size_t)RING * BATCH * HID * 2);
  u16* ln2o      = (u16*)alloc((size_t)RING * BATCH * HID * 2);
  u16* h3        = (u16*)alloc((size_t)2 * BATCH * HID * 2);          // ping-pong

  if (off > ws_size) {
    sentinel_kernel<<<1, 1, 0, stream>>>(out);
    return;
  }

  hipMemsetAsync(flags, 0, 160 * sizeof(int), stream);

  auto cast = [&](const float* src, u16* dst, int n) {
    cast_f32_bf16<<<(n + 2047) / 2048, 256, 0, stream>>>(src, dst, n);
  };
  cast(x,        xbf,        BATCH * T_SEQ * 256);
  cast(lstm_wih, lstm_wih_b, 2048 * 256);
  cast(lstm_whh, lstm_whh_b, 2048 * 512);
  cast(gru_wih,  gru_wih_b,  1536 * 512);
  cast(gru_whh,  gru_whh_b,  1536 * 512);
  cast(rnn_wih,  rnn_wih_b,  512 * 512);
  cast(rnn_whh,  rnn_whh_b,  512 * 512);
  cast(fc_w,     fc_w_b,     1000 * 512);

  const int M64 = (BATCH * T_SEQ) / 64;  // 512
  gemm_xg<<<dim3(M64, 2048 / 64), 256, 0, stream>>>(
      xbf, lstm_wih_b, lstm_bih, lstm_bhh, xg2, 2048, 256, 1024, 1);

  // >64KB dynamic LDS needs the attribute; 117.8KB forces 1 WG/CU.
  hipFuncSetAttribute(reinterpret_cast<const void*>(&fused_kernel),
                      hipFuncAttributeMaxDynamicSharedMemorySize, SM_TOT);
  fused_kernel<<<104, 256, SM_TOT, stream>>>(
      xg2, lstm_whh_b,
      gru_wih_b, gru_whh_b, gru_bih, gru_bhh,
      rnn_wih_b, rnn_whh_b, rnn_bih, rnn_bhh,
      ln1_g, ln1_b, ln2_g, ln2_b,
      h1, ln1o, h2, ln2o, h3, flags);

  // h3 last written slot = (T_SEQ-1)&1 = 1
  fc_kernel<<<(BATCH * 1000 + 255) / 256, 256, 0, stream>>>(
      h3 + (size_t)BATCH * HID, fc_w_b, fc_b, out);
}

// Round 9
// 10201.643 us; speedup vs baseline: 1.5104x; 1.1058x over previous
//
#include <hip/hip_runtime.h>
#include <stdint.h>

#define T_SEQ 1024
#define BATCH 32
#define HID   512
#define RING  32     // inter-stage ring depth (power of 2)

typedef unsigned short u16;
typedef unsigned long long u64;
typedef short bf16x8 __attribute__((ext_vector_type(8)));
typedef float f32x4  __attribute__((ext_vector_type(4)));

__device__ __forceinline__ float bf2f(u16 u) {
  union { unsigned u; float f; } v; v.u = ((unsigned)u) << 16; return v.f;
}
__device__ __forceinline__ u16 f2bf(float f) {
  union { float f; unsigned u; } v; v.f = f;
  unsigned r = v.u + 0x7fffu + ((v.u >> 16) & 1u);   // RNE
  return (u16)(r >> 16);
}
__device__ __forceinline__ float sigf(float x) { return 1.0f / (1.0f + __expf(-x)); }
__device__ __forceinline__ float tanh_fast(float x) { return 2.0f * sigf(2.0f * x) - 1.0f; }

// Device-scope coherent 8B load/store: bypass stale per-XCD L2, no wbl2/inv.
__device__ __forceinline__ u64 ld_dev(const u64* p) {
  return __hip_atomic_load(p, __ATOMIC_RELAXED, __HIP_MEMORY_SCOPE_AGENT);
}
__device__ __forceinline__ void st_dev(u64* p, u64 v) {
  __hip_atomic_store(p, v, __ATOMIC_RELAXED, __HIP_MEMORY_SCOPE_AGENT);
}
__device__ __forceinline__ int ld_flag(const int* p) {
  return __hip_atomic_load(p, __ATOMIC_RELAXED, __HIP_MEMORY_SCOPE_AGENT);
}
// wait until flags f[0..n) all >= target (lanes >= n auto-pass)
__device__ __forceinline__ void poll_ge(const int* f, int n, int target) {
  int lane = threadIdx.x & 63;
  while (true) {
    int v = target;
    if (lane < n) v = ld_flag(&f[lane]);
    if (__all(v >= target)) break;
    __builtin_amdgcn_s_sleep(1);
  }
  __asm__ volatile("" ::: "memory");
}

// ---------------- cast fp32 -> bf16 ----------------
__global__ __launch_bounds__(256) void cast_f32_bf16(const float* __restrict__ in,
                                                     u16* __restrict__ out, int n) {
  int i = (blockIdx.x * 256 + threadIdx.x) * 8;
  if (i + 7 < n) {
    float4 v0 = *reinterpret_cast<const float4*>(in + i);
    float4 v1 = *reinterpret_cast<const float4*>(in + i + 4);
    uint4 o;
    o.x = (unsigned)f2bf(v0.x) | ((unsigned)f2bf(v0.y) << 16);
    o.y = (unsigned)f2bf(v0.z) | ((unsigned)f2bf(v0.w) << 16);
    o.z = (unsigned)f2bf(v1.x) | ((unsigned)f2bf(v1.y) << 16);
    o.w = (unsigned)f2bf(v1.z) | ((unsigned)f2bf(v1.w) << 16);
    *reinterpret_cast<uint4*>(out + i) = o;
  } else {
    for (; i < n; ++i) out[i] = f2bf(in[i]);
  }
}

// ---------------- LSTM input GEMM: out[t][b][k][g] = x @ w_ih^T + b_ih + b_hh ----------------
__global__ __launch_bounds__(256) void gemm_xg(
    const u16* __restrict__ A, const u16* __restrict__ W,
    const float* __restrict__ bias1, const float* __restrict__ bias2,
    u16* __restrict__ out, int N, int K, int strideB, int strideT)
{
  __shared__ u16 As[64][72];
  __shared__ u16 Bs[64][72];
  int tid  = threadIdx.x;
  int lane = tid & 63;
  int wave = tid >> 6;
  int m0 = blockIdx.x * 64;
  int n0 = blockIdx.y * 64;

  f32x4 zero = {0.f, 0.f, 0.f, 0.f};
  f32x4 acc[4] = {zero, zero, zero, zero};

  int srow = tid >> 2;
  int scol = (tid & 3) * 16;

  int m_s = m0 + srow;
  long arow = (long)(m_s & (BATCH - 1)) * strideB + (long)(m_s >> 5) * strideT;
  const u16* aptr = A + arow * K + scol;
  const u16* wptr = W + (long)(n0 + srow) * K + scol;

  for (int kk = 0; kk < K; kk += 64) {
    __syncthreads();
    uint4 a0 = *reinterpret_cast<const uint4*>(aptr + kk);
    uint4 a1 = *reinterpret_cast<const uint4*>(aptr + kk + 8);
    uint4 b0 = *reinterpret_cast<const uint4*>(wptr + kk);
    uint4 b1 = *reinterpret_cast<const uint4*>(wptr + kk + 8);
    *reinterpret_cast<uint4*>(&As[srow][scol])     = a0;
    *reinterpret_cast<uint4*>(&As[srow][scol + 8]) = a1;
    *reinterpret_cast<uint4*>(&Bs[srow][scol])     = b0;
    *reinterpret_cast<uint4*>(&Bs[srow][scol + 8]) = b1;
    __syncthreads();
    int am = wave * 16 + (lane & 15);
    int kq = (lane >> 4) * 8;
#pragma unroll
    for (int ks = 0; ks < 2; ++ks) {
      bf16x8 af = *reinterpret_cast<const bf16x8*>(&As[am][kq + ks * 32]);
#pragma unroll
      for (int nb = 0; nb < 4; ++nb) {
        bf16x8 bf = *reinterpret_cast<const bf16x8*>(&Bs[nb * 16 + (lane & 15)][kq + ks * 32]);
        acc[nb] = __builtin_amdgcn_mfma_f32_16x16x32_bf16(af, bf, acc[nb], 0, 0, 0);
      }
    }
  }
  int quad = lane >> 4;
#pragma unroll
  for (int nb = 0; nb < 4; ++nb) {
    int n = n0 + nb * 16 + (lane & 15);
    float bv = bias1[n] + (bias2 ? bias2[n] : 0.0f);
    int g = n >> 9, k = n & 511;
#pragma unroll
    for (int r = 0; r < 4; ++r) {
      int m = m0 + wave * 16 + quad * 4 + r;
      int t = m >> 5, b = m & (BATCH - 1);
      out[(((long)t * BATCH + b) * HID + k) * 4 + g] = f2bf(acc[nb][r] + bv);
    }
  }
}

// 16x16x32 K=512 tile from pre-loaded A registers + LDS B.
__device__ __forceinline__ f32x4 tile_mm(const u64* A, const u16 (*w)[520], int wrow, int kq) {
  f32x4 a0 = {0.f,0.f,0.f,0.f}, a1 = {0.f,0.f,0.f,0.f};
#pragma unroll
  for (int ks = 0; ks < 16; ++ks) {
    union { u64 q[2]; bf16x8 v; } c;
    c.q[0] = A[2 * ks]; c.q[1] = A[2 * ks + 1];
    bf16x8 bv = *reinterpret_cast<const bf16x8*>(&w[wrow][kq + ks * 32]);
    if (ks & 1) a1 = __builtin_amdgcn_mfma_f32_16x16x32_bf16(c.v, bv, a1, 0, 0, 0);
    else        a0 = __builtin_amdgcn_mfma_f32_16x16x32_bf16(c.v, bv, a0, 0, 0, 0);
  }
  return a0 + a1;
}

// ---------------- persistent recurrent role (ROLE: 0=LSTM 1=GRU 2=RNN) ----------------
// 64 WGs/layer, 8 h-units each. Operand-parallel waves: waves 0-1 gather own-h
// (mt=0/1) and compute all column tiles; waves 2-3 do the same for upstream.
// Each wave loads its 16 A-rows exactly once (no nt duplication).
template <int ROLE>
__device__ void recur_role(
    int wg, const u16* __restrict__ xg, const u16* __restrict__ up,
    const u16* __restrict__ wih, const u16* __restrict__ whh,
    const float* __restrict__ bih, const float* __restrict__ bhh,
    u16* __restrict__ hist, const int* fl_up, int n_up, int* fl_own,
    const int* cons, int n_cons,
    u16 (*w_lds)[520], float (*gx)[33], float (*gh)[33], u16 (*hs)[8])
{
  constexpr int NG = (ROLE == 0) ? 4 : (ROLE == 1) ? 3 : 1;
  constexpr int NT = (ROLE == 2) ? 1 : 2;          // 16-wide column tiles
  constexpr int XROWS = (ROLE > 0) ? NG * 8 : 0;   // x-weight rows staged
  constexpr int TOT = XROWS + NG * 8;
  constexpr int RH = (ROLE == 2) ? 2 : RING;
  int tid = threadIdx.x, lane = tid & 63, wave = tid >> 6;
  int hbase = wg * 8;

  // stage weights: rows [0,XROWS) = W_ih slice, [XROWS,TOT) = W_hh slice
  for (int idx = tid; idx < TOT * 64; idx += 256) {
    int row = idx >> 6, chunk = idx & 63;
    int n = (row < XROWS) ? row : (row - XROWS);
    const u16* src = (row < XROWS) ? wih : whh;
    int g = n >> 3, dd = n & 7;
    uint4 v = *reinterpret_cast<const uint4*>(src + ((long)(g * 512 + hbase + dd)) * 512 + chunk * 8);
    *reinterpret_cast<uint4*>(&w_lds[row][chunk * 8]) = v;
  }
  __syncthreads();

  bool isOwn = (wave < 2);
  int mt = wave & 1;
  bool mact = isOwn || (ROLE > 0);       // up-waves idle for LSTM
  int arow = mt * 16 + (lane & 15);
  int kq = (lane >> 4) * 8;
  int quad = lane >> 4;

  // per-tile bias for this wave's output columns
  float bias_t[NT];
#pragma unroll
  for (int j = 0; j < NT; ++j) {
    bias_t[j] = 0.f;
    int colw = j * 16 + (lane & 15);
    if (colw < NG * 8) {
      int n = (colw >> 3) * 512 + hbase + (colw & 7);
      if constexpr (ROLE == 1) bias_t[j] = isOwn ? bhh[n] : bih[n];
      if constexpr (ROLE == 2) bias_t[j] = isOwn ? 0.f : (bih[n] + bhh[n]);
      (void)n;
    }
  }

  int b_c = tid >> 3, d_c = tid & 7;     // cell thread owns h[b_c][hbase+d_c]
  float c_st = 0.f, h_st = 0.f;

  for (int t = 0; t < T_SEQ; ++t) {
    u64 xq = 0;
    if constexpr (ROLE == 0)
      xq = *reinterpret_cast<const u64*>(xg + (((long)t * BATCH + b_c) * HID + hbase + d_c) * 4);

    if (mact) {
      u64 A[32];
      bool have = false;
      if (isOwn) {
        if (t > 0) {
          poll_ge(fl_own, 64, t);
          const u64* p = reinterpret_cast<const u64*>(
              hist + ((long)((t - 1) & (RH - 1)) * BATCH + arow) * HID + kq);
#pragma unroll
          for (int i = 0; i < 16; ++i) { A[2*i] = ld_dev(p + i*8); A[2*i+1] = ld_dev(p + i*8 + 1); }
          have = true;
        }
      } else {
        poll_ge(fl_up, n_up, t + 1);
        const u64* p = reinterpret_cast<const u64*>(
            up + ((long)(t & (RING - 1)) * BATCH + arow) * HID + kq);
#pragma unroll
        for (int i = 0; i < 16; ++i) { A[2*i] = ld_dev(p + i*8); A[2*i+1] = ld_dev(p + i*8 + 1); }
        have = true;
      }
      const u16 (*wbase)[520] = isOwn ? (w_lds + XROWS) : w_lds;
      float (*outb)[33] = isOwn ? gh : gx;
#pragma unroll
      for (int j = 0; j < NT; ++j) {
        int colw = j * 16 + (lane & 15);
        int wr = (colw < NG * 8) ? colw : (NG * 8 - 1);
        f32x4 acc = {0.f, 0.f, 0.f, 0.f};
        if (have) acc = tile_mm(A, wbase, wr, kq);
#pragma unroll
        for (int r = 0; r < 4; ++r)
          outb[mt * 16 + quad * 4 + r][colw] = acc[r] + bias_t[j];
      }
    }
    __syncthreads();

    // ---- cell ----
    float hnew;
    if constexpr (ROLE == 0) {
      float xv0 = bf2f((u16)(xq));
      float xv1 = bf2f((u16)(xq >> 16));
      float xv2 = bf2f((u16)(xq >> 32));
      float xv3 = bf2f((u16)(xq >> 48));
      float ig = sigf(xv0 + gh[b_c][0 * 8 + d_c]);
      float fg = sigf(xv1 + gh[b_c][1 * 8 + d_c]);
      float gg = tanh_fast(xv2 + gh[b_c][2 * 8 + d_c]);
      float og = sigf(xv3 + gh[b_c][3 * 8 + d_c]);
      c_st = fg * c_st + ig * gg;
      hnew = og * tanh_fast(c_st);
    } else if constexpr (ROLE == 1) {
      float r = sigf(gx[b_c][0 * 8 + d_c] + gh[b_c][0 * 8 + d_c]);
      float z = sigf(gx[b_c][1 * 8 + d_c] + gh[b_c][1 * 8 + d_c]);
      float n = tanh_fast(gx[b_c][2 * 8 + d_c] + r * gh[b_c][2 * 8 + d_c]);
      hnew = (1.f - z) * n + z * h_st;
      h_st = hnew;
    } else {
      hnew = tanh_fast(gx[b_c][d_c] + gh[b_c][d_c]);
    }
    hs[b_c][d_c] = f2bf(hnew);
    __syncthreads();

    // ---- publish (wave0) ----
    if (wave == 0) {
      if (cons != nullptr && t >= RH) {   // ring back-pressure (rarely binds)
        poll_ge(cons, n_cons, t - RH + 1);
      }
      int pb = lane >> 1, half = lane & 1;
      u64 val = *reinterpret_cast<const u64*>(&hs[pb][half * 4]);
      st_dev(reinterpret_cast<u64*>(hist + ((long)(t & (RH - 1)) * BATCH + pb) * HID + hbase + half * 4), val);
      __asm__ volatile("s_waitcnt vmcnt(0)" ::: "memory");
      if (tid == 0)
        __hip_atomic_store(&fl_own[wg], t + 1, __ATOMIC_RELAXED, __HIP_MEMORY_SCOPE_AGENT);
    }
  }
}

// ---------------- pipelined LayerNorm role (4 WGs x 8 rows) ----------------
__device__ void ln_role(int wg, const u16* __restrict__ in, u16* __restrict__ out,
                        const float* __restrict__ gv, const float* __restrict__ bv,
                        const int* fl_in, int* fl_out, const int* cons)
{
  int tid = threadIdx.x, lane = tid & 63, wave = tid >> 6;
  int row = wg * 8 + wave * 2 + (lane >> 5);
  int l32 = lane & 31, k0 = l32 * 16;
  float gr[16], br[16];
#pragma unroll
  for (int j = 0; j < 16; ++j) { gr[j] = gv[k0 + j]; br[j] = bv[k0 + j]; }

  for (int t = 0; t < T_SEQ; ++t) {
    poll_ge(fl_in, 64, t + 1);
    if (t >= RING) poll_ge(cons, 64, t - RING + 1);
    const u64* p = reinterpret_cast<const u64*>(in + ((long)(t & (RING - 1)) * BATCH + row) * HID + k0);
    u64 q[4];
#pragma unroll
    for (int i = 0; i < 4; ++i) q[i] = ld_dev(p + i);
    float x[16];
#pragma unroll
    for (int i = 0; i < 16; ++i) x[i] = bf2f((u16)(q[i >> 2] >> (16 * (i & 3))));
    float s = 0.f, s2 = 0.f;
#pragma unroll
    for (int i = 0; i < 16; ++i) { s += x[i]; s2 += x[i] * x[i]; }
#pragma unroll
    for (int off = 1; off < 32; off <<= 1) { s += __shfl_xor(s, off); s2 += __shfl_xor(s2, off); }
    float mu = s * (1.f / 512.f);
    float var = s2 * (1.f / 512.f) - mu * mu;
    float rs = rsqrtf(var + 1e-5f);
    u16 o[16];
#pragma unroll
    for (int i = 0; i < 16; ++i) o[i] = f2bf((x[i] - mu) * rs * gr[i] + br[i]);
    u64* po = reinterpret_cast<u64*>(out + ((long)(t & (RING - 1)) * BATCH + row) * HID + k0);
    const u64* oq = reinterpret_cast<const u64*>(o);
#pragma unroll
    for (int i = 0; i < 4; ++i) st_dev(po + i, oq[i]);
    __asm__ volatile("s_waitcnt vmcnt(0)" ::: "memory");
    __syncthreads();
    if (tid == 0)
      __hip_atomic_store(&fl_out[wg], t + 1, __ATOMIC_RELAXED, __HIP_MEMORY_SCOPE_AGENT);
  }
}

// ---------------- fused pipeline kernel: 200 WGs ----------------
// flags: [0..63] lstm, [64..67] ln1, [128..191] gru, [192..195] ln2, [256..319] rnn
__global__ __launch_bounds__(256) void fused_kernel(
    const u16* __restrict__ xg, const u16* __restrict__ lstm_whh,
    const u16* __restrict__ gru_wih, const u16* __restrict__ gru_whh,
    const float* __restrict__ gru_bih, const float* __restrict__ gru_bhh,
    const u16* __restrict__ rnn_wih, const u16* __restrict__ rnn_whh,
    const float* __restrict__ rnn_bih, const float* __restrict__ rnn_bhh,
    const float* __restrict__ ln1_g, const float* __restrict__ ln1_b,
    const float* __restrict__ ln2_g, const float* __restrict__ ln2_b,
    u16* h1, u16* ln1o, u16* h2, u16* ln2o, u16* h3, int* fl)
{
  __shared__ u16 w_lds[48][520];     // 49.9 KB  (total static ~58.9 KB)
  __shared__ float gx[32][33];       // 4.2 KB
  __shared__ float gh[32][33];       // 4.2 KB
  __shared__ u16 hs[32][8];          // 0.5 KB
  int bid = blockIdx.x;
  if (bid < 64)
    recur_role<0>(bid, xg, nullptr, nullptr, lstm_whh, nullptr, nullptr,
                  h1, nullptr, 0, fl + 0, fl + 64, 4, w_lds, gx, gh, hs);
  else if (bid < 68)
    ln_role(bid - 64, h1, ln1o, ln1_g, ln1_b, fl + 0, fl + 64, fl + 128);
  else if (bid < 132)
    recur_role<1>(bid - 68, nullptr, ln1o, gru_wih, gru_whh, gru_bih, gru_bhh,
                  h2, fl + 64, 4, fl + 128, fl + 192, 4, w_lds, gx, gh, hs);
  else if (bid < 136)
    ln_role(bid - 132, h2, ln2o, ln2_g, ln2_b, fl + 128, fl + 192, fl + 256);
  else
    recur_role<2>(bid - 136, nullptr, ln2o, rnn_wih, rnn_whh, rnn_bih, rnn_bhh,
                  h3, fl + 192, 4, fl + 256, nullptr, 0, w_lds, gx, gh, hs);
}

// ---------------- final FC ----------------
__global__ __launch_bounds__(256) void fc_kernel(
    const u16* __restrict__ hlast, const u16* __restrict__ w,
    const float* __restrict__ bias, float* __restrict__ out)
{
  int tg = blockIdx.x * 256 + threadIdx.x;
  if (tg >= BATCH * 1000) return;
  int b = tg / 1000, o = tg % 1000;
  const u16* hp = hlast + (long)b * HID;
  const u16* wp = w + (long)o * HID;
  float acc = 0.f;
  for (int k = 0; k < HID; k += 8) {
    uint4 hu = *reinterpret_cast<const uint4*>(hp + k);
    uint4 wu = *reinterpret_cast<const uint4*>(wp + k);
    u16* hsv = reinterpret_cast<u16*>(&hu);
    u16* wsv = reinterpret_cast<u16*>(&wu);
#pragma unroll
    for (int i = 0; i < 8; ++i) acc += bf2f(hsv[i]) * bf2f(wsv[i]);
  }
  out[tg] = acc + bias[o];
}

__global__ void sentinel_kernel(float* out) { out[0] = 12345.0f; }

// ---------------- launch ----------------
extern "C" void kernel_launch(void* const* d_in, const int* in_sizes, int n_in,
                              void* d_out, int out_size, void* d_ws, size_t ws_size,
                              hipStream_t stream)
{
  (void)in_sizes; (void)n_in; (void)out_size;
  const float* x        = (const float*)d_in[0];
  const float* lstm_wih = (const float*)d_in[1];
  const float* lstm_whh = (const float*)d_in[2];
  const float* lstm_bih = (const float*)d_in[3];
  const float* lstm_bhh = (const float*)d_in[4];
  const float* ln1_g    = (const float*)d_in[5];
  const float* ln1_b    = (const float*)d_in[6];
  const float* gru_wih  = (const float*)d_in[7];
  const float* gru_whh  = (const float*)d_in[8];
  const float* gru_bih  = (const float*)d_in[9];
  const float* gru_bhh  = (const float*)d_in[10];
  const float* ln2_g    = (const float*)d_in[11];
  const float* ln2_b    = (const float*)d_in[12];
  const float* rnn_wih  = (const float*)d_in[13];
  const float* rnn_whh  = (const float*)d_in[14];
  const float* rnn_bih  = (const float*)d_in[15];
  const float* rnn_bhh  = (const float*)d_in[16];
  const float* fc_w     = (const float*)d_in[17];
  const float* fc_b     = (const float*)d_in[18];
  float* out = (float*)d_out;

  char* ws = (char*)d_ws;
  size_t off = 0;
  auto alloc = [&](size_t bytes) -> void* {
    void* p = ws + off; off += (bytes + 255) & ~(size_t)255; return p;
  };
  int* flags     = (int*)alloc(320 * sizeof(int));
  u16* xbf       = (u16*)alloc((size_t)BATCH * T_SEQ * 256 * 2);
  u16* lstm_wih_b= (u16*)alloc((size_t)2048 * 256 * 2);
  u16* lstm_whh_b= (u16*)alloc((size_t)2048 * 512 * 2);
  u16* gru_wih_b = (u16*)alloc((size_t)1536 * 512 * 2);
  u16* gru_whh_b = (u16*)alloc((size_t)1536 * 512 * 2);
  u16* rnn_wih_b = (u16*)alloc((size_t)512 * 512 * 2);
  u16* rnn_whh_b = (u16*)alloc((size_t)512 * 512 * 2);
  u16* fc_w_b    = (u16*)alloc((size_t)1000 * 512 * 2);
  u16* xg2       = (u16*)alloc((size_t)T_SEQ * BATCH * HID * 4 * 2);  // 128 MB
  u16* h1        = (u16*)alloc((size_t)RING * BATCH * HID * 2);       // 1 MB rings
  u16* ln1o      = (u16*)alloc((size_t)RING * BATCH * HID * 2);
  u16* h2        = (u16*)alloc((size_t)RING * BATCH * HID * 2);
  u16* ln2o      = (u16*)alloc((size_t)RING * BATCH * HID * 2);
  u16* h3        = (u16*)alloc((size_t)2 * BATCH * HID * 2);          // ping-pong

  if (off > ws_size) {
    sentinel_kernel<<<1, 1, 0, stream>>>(out);
    return;
  }

  hipMemsetAsync(flags, 0, 320 * sizeof(int), stream);

  auto cast = [&](const float* src, u16* dst, int n) {
    cast_f32_bf16<<<(n + 2047) / 2048, 256, 0, stream>>>(src, dst, n);
  };
  cast(x,        xbf,        BATCH * T_SEQ * 256);
  cast(lstm_wih, lstm_wih_b, 2048 * 256);
  cast(lstm_whh, lstm_whh_b, 2048 * 512);
  cast(gru_wih,  gru_wih_b,  1536 * 512);
  cast(gru_whh,  gru_whh_b,  1536 * 512);
  cast(rnn_wih,  rnn_wih_b,  512 * 512);
  cast(rnn_whh,  rnn_whh_b,  512 * 512);
  cast(fc_w,     fc_w_b,     1000 * 512);

  const int M64 = (BATCH * T_SEQ) / 64;  // 512
  gemm_xg<<<dim3(M64, 2048 / 64), 256, 0, stream>>>(
      xbf, lstm_wih_b, lstm_bih, lstm_bhh, xg2, 2048, 256, 1024, 1);

  fused_kernel<<<200, 256, 0, stream>>>(
      xg2, lstm_whh_b,
      gru_wih_b, gru_whh_b, gru_bih, gru_bhh,
      rnn_wih_b, rnn_whh_b, rnn_bih, rnn_bhh,
      ln1_g, ln1_b, ln2_g, ln2_b,
      h1, ln1o, h2, ln2o, h3, flags);

  // h3 last written slot = (T_SEQ-1)&1 = 1
  fc_kernel<<<(BATCH * 1000 + 255) / 256, 256, 0, stream>>>(
      h3 + (size_t)BATCH * HID, fc_w_b, fc_b, out);
}